// Round 11
// baseline (293.568 us; speedup 1.0000x reference)
//
#include <hip/hip_runtime.h>
#include <hip/hip_bf16.h>

typedef unsigned short u16;
typedef __attribute__((ext_vector_type(8))) __bf16 bf16x8;
typedef __attribute__((ext_vector_type(4))) float f32x4;
typedef __attribute__((ext_vector_type(2))) unsigned int u32x2;

#define MODEL_DIM 1024
#define NUM_HEADS 16
#define HEAD_DIM  64
#define BATCH     4
#define SEQ       2048
#define ROWS      (BATCH*SEQ)     // 8192

static __device__ __forceinline__ u16 f2bf(float f) {
    union { __hip_bfloat16 h; u16 u; } cv;
    cv.h = __float2bfloat16(f);
    return cv.u;
}
static __device__ __forceinline__ float bf2f(u16 u) {
    union { unsigned int i; float f; } cv;
    cv.i = ((unsigned int)u) << 16;
    return cv.f;
}

static __device__ __forceinline__ void gload16(const u16* g, unsigned lds_byte) {
    __builtin_amdgcn_global_load_lds(
        (const __attribute__((address_space(1))) unsigned int*)g,
        (__attribute__((address_space(3))) unsigned int*)(uintptr_t)lds_byte,
        16, 0, 0);
}

// ---------------- fused cast f32 -> bf16 (x + 4 weights, contiguous out) ----
__global__ void castk_all(const float* __restrict__ x,
                          const float* __restrict__ w0, const float* __restrict__ w1,
                          const float* __restrict__ w2, const float* __restrict__ w3,
                          u16* __restrict__ out) {
    const int total = ROWS * MODEL_DIM + 4 * MODEL_DIM * MODEL_DIM;  // 12.58M
    int i = (blockIdx.x * blockDim.x + threadIdx.x) * 4;
    int stride = gridDim.x * blockDim.x * 4;
    for (; i < total; i += stride) {
        const float* src;
        int off;
        if (i < ROWS * MODEL_DIM) { src = x; off = i; }
        else {
            int j = i - ROWS * MODEL_DIM;
            int w = j >> 20;
            off = j & 1048575;
            src = (w == 0) ? w0 : (w == 1) ? w1 : (w == 2) ? w2 : w3;
        }
        float4 v = *reinterpret_cast<const float4*>(src + off);
        ushort4 o;
        o.x = f2bf(v.x); o.y = f2bf(v.y); o.z = f2bf(v.z); o.w = f2bf(v.w);
        *reinterpret_cast<ushort4*>(out + i) = o;
    }
}

// ---------------- NT GEMM core (gload_lds + XOR-swizzle staging) ----------
#define BM 128
#define BN 128
#define BK 64

static __device__ __forceinline__ void stage_tile(const u16* gbase, int K,
                                                  unsigned lds_byte_base, int t) {
#pragma unroll
    for (int ti = 0; ti < 4; ti++) {
        int o    = t * 8 + ti * 2048;
        int row  = o >> 6;
        int colb = ((o & 63) * 2) ^ ((row & 7) << 4);
        gload16(gbase + (size_t)row * K + (colb >> 1), lds_byte_base + o * 2);
    }
}

static __device__ __forceinline__ bf16x8 frag_read(const char* base, int row, int h,
                                                   int lo, int hi) {
    return *reinterpret_cast<const bf16x8*>(
        base + row * 128 + ((h * 64 + hi * 16) ^ ((lo & 7) << 4)));
}

// fused QKV projection: grid (M/128, 24); Q pre-scaled by 0.125*log2(e)
__global__ __launch_bounds__(256) void gemm_qkv(
    const u16* __restrict__ A,
    const u16* __restrict__ Wq, const u16* __restrict__ Wk, const u16* __restrict__ Wv,
    u16* __restrict__ qO, u16* __restrict__ kO, u16* __restrict__ vO)
{
    __shared__ u16 As[BM * BK];
    __shared__ u16 Bs[BN * BK];
    const int t    = threadIdx.x;
    const int wid  = t >> 6;
    const int lane = t & 63;
    const int lo   = lane & 15, hi = lane >> 4;
    const int bm   = blockIdx.x * BM;
    const int mat  = blockIdx.y >> 3;
    const int bn   = (blockIdx.y & 7) * BN;
    const u16* W   = (mat == 0) ? Wq : (mat == 1) ? Wk : Wv;
    u16* outB      = (mat == 0) ? qO : (mat == 1) ? kO : vO;
    const float qscale = (mat == 0) ? 0.18033688f : 1.0f;   // 0.125*log2(e)
    const int wr   = wid >> 1, wc = wid & 1;
    const int K = MODEL_DIM;
    const unsigned AsB = (unsigned)(uintptr_t)As;
    const unsigned BsB = (unsigned)(uintptr_t)Bs;

    f32x4 acc[4][4];
#pragma unroll
    for (int m = 0; m < 4; m++)
#pragma unroll
        for (int n = 0; n < 4; n++) acc[m][n] = (f32x4){0.f, 0.f, 0.f, 0.f};

    for (int k0 = 0; k0 < K; k0 += BK) {
        __syncthreads();
        stage_tile(A + (size_t)bm * K + k0, K, AsB, t);
        stage_tile(W + (size_t)bn * K + k0, K, BsB, t);
        __syncthreads();
#pragma unroll
        for (int h = 0; h < 2; h++) {
            bf16x8 af[4], bfr[4];
#pragma unroll
            for (int m = 0; m < 4; m++)
                af[m] = frag_read((const char*)As, wr * 64 + m * 16 + lo, h, lo, hi);
#pragma unroll
            for (int n = 0; n < 4; n++)
                bfr[n] = frag_read((const char*)Bs, wc * 64 + n * 16 + lo, h, lo, hi);
#pragma unroll
            for (int m = 0; m < 4; m++)
#pragma unroll
                for (int n = 0; n < 4; n++)
                    acc[m][n] = __builtin_amdgcn_mfma_f32_16x16x32_bf16(af[m], bfr[n], acc[m][n], 0, 0, 0);
        }
    }

#pragma unroll
    for (int m = 0; m < 4; m++)
#pragma unroll
        for (int n = 0; n < 4; n++)
#pragma unroll
            for (int r = 0; r < 4; r++) {
                int row = bm + wr * 64 + m * 16 + hi * 4 + r;
                int col = bn + wc * 64 + n * 16 + lo;
                int b = row >> 11, np = row & 2047;
                int hh = col >> 6, dd = col & 63;
                outB[(((size_t)(b * NUM_HEADS + hh) * SEQ + np) << 6) + dd] = f2bf(acc[m][n][r] * qscale);
            }
}

// out-projection: C = A * Wo^T + bias, f32 out
__global__ __launch_bounds__(256) void gemm_out(
    const u16* __restrict__ A,
    const u16* __restrict__ W,
    float* __restrict__ outF,
    const float* __restrict__ bias)
{
    __shared__ u16 As[BM * BK];
    __shared__ u16 Bs[BN * BK];
    const int t    = threadIdx.x;
    const int wid  = t >> 6;
    const int lane = t & 63;
    const int lo   = lane & 15, hi = lane >> 4;
    const int bm   = blockIdx.x * BM;
    const int bn   = blockIdx.y * BN;
    const int wr   = wid >> 1, wc = wid & 1;
    const int K = MODEL_DIM, N = MODEL_DIM;
    const unsigned AsB = (unsigned)(uintptr_t)As;
    const unsigned BsB = (unsigned)(uintptr_t)Bs;

    f32x4 acc[4][4];
#pragma unroll
    for (int m = 0; m < 4; m++)
#pragma unroll
        for (int n = 0; n < 4; n++) acc[m][n] = (f32x4){0.f, 0.f, 0.f, 0.f};

    for (int k0 = 0; k0 < K; k0 += BK) {
        __syncthreads();
        stage_tile(A + (size_t)bm * K + k0, K, AsB, t);
        stage_tile(W + (size_t)bn * K + k0, K, BsB, t);
        __syncthreads();
#pragma unroll
        for (int h = 0; h < 2; h++) {
            bf16x8 af[4], bfr[4];
#pragma unroll
            for (int m = 0; m < 4; m++)
                af[m] = frag_read((const char*)As, wr * 64 + m * 16 + lo, h, lo, hi);
#pragma unroll
            for (int n = 0; n < 4; n++)
                bfr[n] = frag_read((const char*)Bs, wc * 64 + n * 16 + lo, h, lo, hi);
#pragma unroll
            for (int m = 0; m < 4; m++)
#pragma unroll
                for (int n = 0; n < 4; n++)
                    acc[m][n] = __builtin_amdgcn_mfma_f32_16x16x32_bf16(af[m], bfr[n], acc[m][n], 0, 0, 0);
        }
    }

#pragma unroll
    for (int m = 0; m < 4; m++)
#pragma unroll
        for (int n = 0; n < 4; n++)
#pragma unroll
            for (int r = 0; r < 4; r++) {
                int row = bm + wr * 64 + m * 16 + hi * 4 + r;
                int col = bn + wc * 64 + n * 16 + lo;
                outF[(size_t)row * N + col] = acc[m][n][r] + bias[col];
            }
}

// ---------------- flash attention v11: split-KV chains + merge ------------
// R7 kernel body (proven) with chain decode:
//  g (0..3071): bh = g&63 (4 CUs per bh, XCD-affine), c = g>>6:
//   c<16  : A-chain  qt=16+c,      kv [0..15]   -> partial slot
//   c<32  : single   qt=15-d(c),   kv [0..qt]   -> direct output
//   c<48  : B-chain  qt=31-e(c),   kv [16..qt]  -> partial slot
//  zigzag d/e gives exact 132 KV-iters per CU; 1024 extra blocks = refill.
// Partial slot (8704 B): O[64][64] bf16 normalized + m[64] f32 + l[64] f32.

static __device__ __forceinline__ u32x2 tr16(unsigned int addr) {
    u32x2 r;
    asm volatile("ds_read_b64_tr_b16 %0, %1" : "=v"(r) : "v"(addr));
    return r;
}

__global__ __launch_bounds__(256, 8) void attn(
    const u16* __restrict__ Q,   // [B*H][N][64]
    const u16* __restrict__ Kg,
    const u16* __restrict__ Vg,
    u16* __restrict__ O,         // [B][N][H*64]
    u16* __restrict__ part)      // 2048 slots x 8704 B
{
    __shared__ u16 lds[8192];    // K swizzled @0 (8KB), V subtiled @8KB
    const int t    = threadIdx.x;
    const int wid  = t >> 6, lane = t & 63;
    const int lo   = lane & 15, hi = lane >> 4;

    const int g  = blockIdx.x;            // 0..3071
    const int bh = g & 63;
    const int c  = g >> 6;                // 0..47
    int qt, j0, j1, mode;                 // mode 0=direct 1=A 2=B
    if (c < 16) {
        qt = 16 + c; j0 = 0; j1 = 15; mode = 1;
    } else if (c < 32) {
        int kk = (c - 16) >> 2, aa = c & 3;
        int d = 4 * kk + ((kk & 1) ? 3 - aa : aa);
        qt = 15 - d; j0 = 0; j1 = qt; mode = 0;
    } else {
        int kk = (c - 32) >> 2, aa = c & 3;
        int e = 4 * kk + ((kk & 1) ? 3 - aa : aa);
        qt = 31 - e; j0 = 16; j1 = qt; mode = 2;
    }

    const size_t base = (size_t)bh * SEQ * 64;
    const int qbase = qt * 64 + wid * 16;
    const unsigned ldsb = (unsigned)(uintptr_t)lds;

    // staging geometry (R7 verbatim): pre-swizzled K, subtiled V sources
    int srcK[2], srcV[2];
    unsigned dstK[2], dstV[2];
#pragma unroll
    for (int ti = 0; ti < 2; ti++) {
        int o   = t * 8 + ti * 2048;
        int row = o >> 6;
        int colb = ((o & 63) * 2) ^ ((row & 7) << 4);
        srcK[ti] = row * 64 + (colb >> 1);
        dstK[ti] = ldsb + o * 2;
        int st = o >> 9;
        int kv = (st >> 2) * 32 + ((o >> 4) & 31);
        int d  = (st & 3) * 16 + (o & 15);
        srcV[ti] = kv * 64 + d;
        dstV[ti] = ldsb + 8192 + o * 2;
    }

    // Q fragments (B-operand): lane holds Q[qbase+lo][h*32+hi*8+..] (pre-scaled)
    bf16x8 qf[2];
#pragma unroll
    for (int h = 0; h < 2; h++)
        qf[h] = *reinterpret_cast<const bf16x8*>(Q + base + (size_t)(qbase + lo) * 64 + h * 32 + hi * 8);
    asm volatile("" : "+v"(qf[0]), "+v"(qf[1]));

    float m_run = -3.0e38f, l_part = 0.f;
    f32x4 acc[4];
#pragma unroll
    for (int dt = 0; dt < 4; dt++) acc[dt] = (f32x4){0.f, 0.f, 0.f, 0.f};

    for (int j = j0; j <= j1; j++) {
        __builtin_amdgcn_s_barrier();       // prev-iter readers done
        {
            const u16* Kt = Kg + base + (size_t)j * 4096;
            const u16* Vt = Vg + base + (size_t)j * 4096;
#pragma unroll
            for (int ti = 0; ti < 2; ti++) {
                gload16(Kt + srcK[ti], dstK[ti]);
                gload16(Vt + srcV[ti], dstV[ti]);
            }
        }
        asm volatile("s_waitcnt vmcnt(0)" ::: "memory");
        __builtin_amdgcn_s_barrier();
        __builtin_amdgcn_sched_barrier(0);

        // S^T = K Q^T: lane holds S[q=qbase+lo][kv=j*64+kt*16+hi*4+r]
        f32x4 s[4];
#pragma unroll
        for (int kh = 0; kh < 2; kh++) {
            bf16x8 kfa[2][2];
#pragma unroll
            for (int k2 = 0; k2 < 2; k2++)
#pragma unroll
                for (int h = 0; h < 2; h++)
                    kfa[k2][h] = *reinterpret_cast<const bf16x8*>(
                        (const char*)lds + ((kh * 2 + k2) * 16 + lo) * 128 + ((h * 64 + hi * 16) ^ ((lo & 7) << 4)));
            __builtin_amdgcn_s_setprio(1);
#pragma unroll
            for (int k2 = 0; k2 < 2; k2++) {
                f32x4 a2 = (f32x4){0.f, 0.f, 0.f, 0.f};
#pragma unroll
                for (int h = 0; h < 2; h++)
                    a2 = __builtin_amdgcn_mfma_f32_16x16x32_bf16(kfa[k2][h], qf[h], a2, 0, 0, 0);
                s[kh * 2 + k2] = a2;
            }
            __builtin_amdgcn_s_setprio(0);
        }
        if (j == qt) {                       // diagonal (direct/B chains only)
            const int ql = wid * 16 + lo;
#pragma unroll
            for (int kt = 0; kt < 4; kt++)
#pragma unroll
                for (int r = 0; r < 4; r++)
                    if (kt * 16 + hi * 4 + r > ql) s[kt][r] = -1.0e30f;
        }
        // online softmax (log2 domain, Q pre-scaled), defer-max THR=8
        float vm = s[0][0];
#pragma unroll
        for (int kt = 0; kt < 4; kt++)
#pragma unroll
            for (int r = 0; r < 4; r++) vm = fmaxf(vm, s[kt][r]);
        vm = fmaxf(vm, __shfl_xor(vm, 16));
        vm = fmaxf(vm, __shfl_xor(vm, 32));
        if (!__all(vm <= m_run + 8.0f)) {
            float nm = fmaxf(m_run, vm);
            float sc = exp2f(m_run - nm);
            m_run = nm;
            l_part *= sc;
#pragma unroll
            for (int dt = 0; dt < 4; dt++)
#pragma unroll
                for (int r = 0; r < 4; r++) acc[dt][r] *= sc;   // cols=q=lo: lane-local
        }
        float ps = 0.f;
#pragma unroll
        for (int kt = 0; kt < 4; kt++)
#pragma unroll
            for (int r = 0; r < 4; r++) {
                float p = exp2f(s[kt][r] - m_run);
                s[kt][r] = p;
                ps += p;
            }
        l_part += ps;
        // pack P into PV B-fragments (kappa: e<4 -> kv=4hi+e; e>=4 -> 16+4hi+(e-4))
        bf16x8 pa[2];
        {
            union { u16 uu[8]; bf16x8 v; } q0, q1;
#pragma unroll
            for (int e = 0; e < 4; e++) {
                q0.uu[e]     = f2bf(s[0][e]);
                q0.uu[4 + e] = f2bf(s[1][e]);
                q1.uu[e]     = f2bf(s[2][e]);
                q1.uu[4 + e] = f2bf(s[3][e]);
            }
            pa[0] = q0.v;
            pa[1] = q1.v;
        }

        // PV swapped: acc[dt] = mfma(A=V^T frag, B=P) -> C[row=d][col=q=lo]
        const unsigned vtb = ldsb + 8192u + (unsigned)((hi * 64 + lo * 4) * 2);
#pragma unroll
        for (int pr = 0; pr < 2; pr++) {
            u32x2 tv[2][2][2];
#pragma unroll
            for (int d2 = 0; d2 < 2; d2++)
#pragma unroll
                for (int h = 0; h < 2; h++)
#pragma unroll
                    for (int sel = 0; sel < 2; sel++)
                        tv[d2][h][sel] = tr16(vtb + (unsigned)(((h * 4 + pr * 2 + d2) * 512 + sel * 256) * 2));
            asm volatile("s_waitcnt lgkmcnt(0)" ::: "memory");
            __builtin_amdgcn_sched_barrier(0);
            __builtin_amdgcn_s_setprio(1);
#pragma unroll
            for (int d2 = 0; d2 < 2; d2++) {
#pragma unroll
                for (int h = 0; h < 2; h++) {
                    union { unsigned int w[4]; bf16x8 v; } bv;
                    bv.w[0] = tv[d2][h][0][0];
                    bv.w[1] = tv[d2][h][0][1];
                    bv.w[2] = tv[d2][h][1][0];
                    bv.w[3] = tv[d2][h][1][1];
                    acc[pr * 2 + d2] = __builtin_amdgcn_mfma_f32_16x16x32_bf16(bv.v, pa[h], acc[pr * 2 + d2], 0, 0, 0);
                }
            }
            __builtin_amdgcn_s_setprio(0);
        }
    }

    // epilogue
    float l = l_part;
    l += __shfl_xor(l, 16);
    l += __shfl_xor(l, 32);
    const float inv = 1.0f / l;
    if (mode == 0) {                         // direct output
        const int b = bh >> 4, hh = bh & 15;
        const size_t orow = ((size_t)(b * SEQ + qbase + lo)) * 1024 + hh * 64;
#pragma unroll
        for (int dt = 0; dt < 4; dt++) {
            union { u16 uu[4]; uint2 d2; } pk;
#pragma unroll
            for (int r = 0; r < 4; r++) pk.uu[r] = f2bf(acc[dt][r] * inv);
            *reinterpret_cast<uint2*>(O + orow + dt * 16 + hi * 4) = pk.d2;
        }
    } else {                                 // partial slot
        const int s = ((((bh << 4) | (qt - 16)) << 1) | (mode >> 1));
        char* pbase = (char*)part + (size_t)s * 8704;
        u16* po = (u16*)pbase;
        const int qrow = wid * 16 + lo;
#pragma unroll
        for (int dt = 0; dt < 4; dt++) {
            union { u16 uu[4]; uint2 d2; } pk;
#pragma unroll
            for (int r = 0; r < 4; r++) pk.uu[r] = f2bf(acc[dt][r] * inv);
            *reinterpret_cast<uint2*>(po + qrow * 64 + dt * 16 + hi * 4) = pk.d2;
        }
        if (hi == 0) {
            reinterpret_cast<float*>(pbase + 8192)[qrow] = m_run;
            reinterpret_cast<float*>(pbase + 8448)[qrow] = l;
        }
    }
}

// merge the two partials of each (bh, qt>=16) into final output
__global__ __launch_bounds__(256) void attn_merge(
    const u16* __restrict__ part, u16* __restrict__ O)
{
    const int g  = blockIdx.x;               // 0..1023
    const int bh = g >> 4;
    const int qt = 16 + (g & 15);
    const int t  = threadIdx.x;
    const int row = t >> 2;
    const int d0  = (t & 3) * 16;

    const char* pa = (const char*)part + (size_t)(((bh << 4) | (qt - 16)) << 1) * 8704;
    const char* pb = pa + 8704;
    float mA = reinterpret_cast<const float*>(pa + 8192)[row];
    float lA = reinterpret_cast<const float*>(pa + 8448)[row];
    float mB = reinterpret_cast<const float*>(pb + 8192)[row];
    float lB = reinterpret_cast<const float*>(pb + 8448)[row];
    float M  = fmaxf(mA, mB);
    float wA = exp2f(mA - M) * lA;
    float wB = exp2f(mB - M) * lB;
    float inv = 1.0f / (wA + wB);
    wA *= inv; wB *= inv;

    const u16* oa = (const u16*)pa + row * 64 + d0;
    const u16* ob = (const u16*)pb + row * 64 + d0;
    union { uint4 v; u16 uu[8]; } a0, a1, b0, b1;
    a0.v = *reinterpret_cast<const uint4*>(oa);
    a1.v = *reinterpret_cast<const uint4*>(oa + 8);
    b0.v = *reinterpret_cast<const uint4*>(ob);
    b1.v = *reinterpret_cast<const uint4*>(ob + 8);
    union { u16 uu[8]; uint4 v; } o0, o1;
#pragma unroll
    for (int e = 0; e < 8; e++) {
        o0.uu[e] = f2bf(bf2f(a0.uu[e]) * wA + bf2f(b0.uu[e]) * wB);
        o1.uu[e] = f2bf(bf2f(a1.uu[e]) * wA + bf2f(b1.uu[e]) * wB);
    }
    const int b = bh >> 4, hh = bh & 15;
    const size_t orow = ((size_t)(b * SEQ + qt * 64 + row)) * 1024 + hh * 64 + d0;
    *reinterpret_cast<uint4*>(O + orow)     = o0.v;
    *reinterpret_cast<uint4*>(O + orow + 8) = o1.v;
}

extern "C" void kernel_launch(void* const* d_in, const int* in_sizes, int n_in,
                              void* d_out, int out_size, void* d_ws, size_t ws_size,
                              hipStream_t stream) {
    const float* x  = (const float*)d_in[0];
    const float* Wq = (const float*)d_in[1];
    const float* Wk = (const float*)d_in[2];
    const float* Wv = (const float*)d_in[3];
    const float* Wo = (const float*)d_in[4];
    const float* bo = (const float*)d_in[5];
    float* out = (float*)d_out;

    char* ws = (char*)d_ws;
    u16* xb  = (u16*)ws;                              // 16 MiB, then weights contiguous
    u16* wqb = (u16*)(ws + 16777216);
    u16* wkb = wqb + 1048576;
    u16* wvb = wkb + 1048576;
    u16* wob = wvb + 1048576;                         // ends at 24.1 MB
    u16* q   = (u16*)(ws + 16777216 + 8388608);       // [B][H][N][D] bf16
    u16* k   = q + 8388608;
    u16* v   = k + 8388608;
    u16* ao  = v + 8388608;                           // [B][N][H*64] bf16
    // partials reuse [0, 17.8MB): xb + wq/wk/wv are dead once attn runs
    u16* part = (u16*)ws;

    castk_all<<<3072, 256, 0, stream>>>(x, Wq, Wk, Wv, Wo, xb);

    gemm_qkv<<<dim3(ROWS / BM, 24), 256, 0, stream>>>(xb, wqb, wkb, wvb, q, k, v);

    attn<<<3072, 256, 0, stream>>>(q, k, v, ao, part);
    attn_merge<<<1024, 256, 0, stream>>>(part, ao);

    gemm_out<<<dim3(ROWS / BM, MODEL_DIM / BN), 256, 0, stream>>>(ao, wob, out, bo);
}

// Round 12
// 192.288 us; speedup vs baseline: 1.5267x; 1.5267x over previous
//
#include <hip/hip_runtime.h>
#include <hip/hip_bf16.h>

typedef unsigned short u16;
typedef __attribute__((ext_vector_type(8))) __bf16 bf16x8;
typedef __attribute__((ext_vector_type(4))) float f32x4;
typedef __attribute__((ext_vector_type(2))) unsigned int u32x2;

#define MODEL_DIM 1024
#define NUM_HEADS 16
#define HEAD_DIM  64
#define BATCH     4
#define SEQ       2048
#define ROWS      (BATCH*SEQ)     // 8192

static __device__ __forceinline__ u16 f2bf(float f) {
    union { __hip_bfloat16 h; u16 u; } cv;
    cv.h = __float2bfloat16(f);
    return cv.u;
}

static __device__ __forceinline__ void gload16(const u16* g, unsigned lds_byte) {
    __builtin_amdgcn_global_load_lds(
        (const __attribute__((address_space(1))) unsigned int*)g,
        (__attribute__((address_space(3))) unsigned int*)(uintptr_t)lds_byte,
        16, 0, 0);
}

// ---------------- fused cast f32 -> bf16 (x + 4 weights, contiguous out) ----
__global__ void castk_all(const float* __restrict__ x,
                          const float* __restrict__ w0, const float* __restrict__ w1,
                          const float* __restrict__ w2, const float* __restrict__ w3,
                          u16* __restrict__ out) {
    const int total = ROWS * MODEL_DIM + 4 * MODEL_DIM * MODEL_DIM;  // 12.58M
    int i = (blockIdx.x * blockDim.x + threadIdx.x) * 4;
    int stride = gridDim.x * blockDim.x * 4;
    for (; i < total; i += stride) {
        const float* src;
        int off;
        if (i < ROWS * MODEL_DIM) { src = x; off = i; }
        else {
            int j = i - ROWS * MODEL_DIM;
            int w = j >> 20;
            off = j & 1048575;
            src = (w == 0) ? w0 : (w == 1) ? w1 : (w == 2) ? w2 : w3;
        }
        float4 v = *reinterpret_cast<const float4*>(src + off);
        ushort4 o;
        o.x = f2bf(v.x); o.y = f2bf(v.y); o.z = f2bf(v.z); o.w = f2bf(v.w);
        *reinterpret_cast<ushort4*>(out + i) = o;
    }
}

// ---------------- NT GEMM core (gload_lds + XOR-swizzle staging) ----------
#define BM 128
#define BN 128
#define BK 64

static __device__ __forceinline__ void stage_tile(const u16* gbase, int K,
                                                  unsigned lds_byte_base, int t) {
#pragma unroll
    for (int ti = 0; ti < 4; ti++) {
        int o    = t * 8 + ti * 2048;
        int row  = o >> 6;
        int colb = ((o & 63) * 2) ^ ((row & 7) << 4);
        gload16(gbase + (size_t)row * K + (colb >> 1), lds_byte_base + o * 2);
    }
}

static __device__ __forceinline__ bf16x8 frag_read(const char* base, int row, int h,
                                                   int lo, int hi) {
    return *reinterpret_cast<const bf16x8*>(
        base + row * 128 + ((h * 64 + hi * 16) ^ ((lo & 7) << 4)));
}

// fused QKV projection: grid (M/128, 24); Q pre-scaled by 0.125*log2(e)
__global__ __launch_bounds__(256) void gemm_qkv(
    const u16* __restrict__ A,
    const u16* __restrict__ Wq, const u16* __restrict__ Wk, const u16* __restrict__ Wv,
    u16* __restrict__ qO, u16* __restrict__ kO, u16* __restrict__ vO)
{
    __shared__ u16 As[BM * BK];
    __shared__ u16 Bs[BN * BK];
    const int t    = threadIdx.x;
    const int wid  = t >> 6;
    const int lane = t & 63;
    const int lo   = lane & 15, hi = lane >> 4;
    const int bm   = blockIdx.x * BM;
    const int mat  = blockIdx.y >> 3;
    const int bn   = (blockIdx.y & 7) * BN;
    const u16* W   = (mat == 0) ? Wq : (mat == 1) ? Wk : Wv;
    u16* outB      = (mat == 0) ? qO : (mat == 1) ? kO : vO;
    const float qscale = (mat == 0) ? 0.18033688f : 1.0f;   // 0.125*log2(e)
    const int wr   = wid >> 1, wc = wid & 1;
    const int K = MODEL_DIM;
    const unsigned AsB = (unsigned)(uintptr_t)As;
    const unsigned BsB = (unsigned)(uintptr_t)Bs;

    f32x4 acc[4][4];
#pragma unroll
    for (int m = 0; m < 4; m++)
#pragma unroll
        for (int n = 0; n < 4; n++) acc[m][n] = (f32x4){0.f, 0.f, 0.f, 0.f};

    for (int k0 = 0; k0 < K; k0 += BK) {
        __syncthreads();
        stage_tile(A + (size_t)bm * K + k0, K, AsB, t);
        stage_tile(W + (size_t)bn * K + k0, K, BsB, t);
        __syncthreads();
#pragma unroll
        for (int h = 0; h < 2; h++) {
            bf16x8 af[4], bfr[4];
#pragma unroll
            for (int m = 0; m < 4; m++)
                af[m] = frag_read((const char*)As, wr * 64 + m * 16 + lo, h, lo, hi);
#pragma unroll
            for (int n = 0; n < 4; n++)
                bfr[n] = frag_read((const char*)Bs, wc * 64 + n * 16 + lo, h, lo, hi);
#pragma unroll
            for (int m = 0; m < 4; m++)
#pragma unroll
                for (int n = 0; n < 4; n++)
                    acc[m][n] = __builtin_amdgcn_mfma_f32_16x16x32_bf16(af[m], bfr[n], acc[m][n], 0, 0, 0);
        }
    }

#pragma unroll
    for (int m = 0; m < 4; m++)
#pragma unroll
        for (int n = 0; n < 4; n++)
#pragma unroll
            for (int r = 0; r < 4; r++) {
                int row = bm + wr * 64 + m * 16 + hi * 4 + r;
                int col = bn + wc * 64 + n * 16 + lo;
                int b = row >> 11, np = row & 2047;
                int hh = col >> 6, dd = col & 63;
                outB[(((size_t)(b * NUM_HEADS + hh) * SEQ + np) << 6) + dd] = f2bf(acc[m][n][r] * qscale);
            }
}

// out-projection: C = A * Wo^T + bias, f32 out
__global__ __launch_bounds__(256) void gemm_out(
    const u16* __restrict__ A,
    const u16* __restrict__ W,
    float* __restrict__ outF,
    const float* __restrict__ bias)
{
    __shared__ u16 As[BM * BK];
    __shared__ u16 Bs[BN * BK];
    const int t    = threadIdx.x;
    const int wid  = t >> 6;
    const int lane = t & 63;
    const int lo   = lane & 15, hi = lane >> 4;
    const int bm   = blockIdx.x * BM;
    const int bn   = blockIdx.y * BN;
    const int wr   = wid >> 1, wc = wid & 1;
    const int K = MODEL_DIM, N = MODEL_DIM;
    const unsigned AsB = (unsigned)(uintptr_t)As;
    const unsigned BsB = (unsigned)(uintptr_t)Bs;

    f32x4 acc[4][4];
#pragma unroll
    for (int m = 0; m < 4; m++)
#pragma unroll
        for (int n = 0; n < 4; n++) acc[m][n] = (f32x4){0.f, 0.f, 0.f, 0.f};

    for (int k0 = 0; k0 < K; k0 += BK) {
        __syncthreads();
        stage_tile(A + (size_t)bm * K + k0, K, AsB, t);
        stage_tile(W + (size_t)bn * K + k0, K, BsB, t);
        __syncthreads();
#pragma unroll
        for (int h = 0; h < 2; h++) {
            bf16x8 af[4], bfr[4];
#pragma unroll
            for (int m = 0; m < 4; m++)
                af[m] = frag_read((const char*)As, wr * 64 + m * 16 + lo, h, lo, hi);
#pragma unroll
            for (int n = 0; n < 4; n++)
                bfr[n] = frag_read((const char*)Bs, wc * 64 + n * 16 + lo, h, lo, hi);
#pragma unroll
            for (int m = 0; m < 4; m++)
#pragma unroll
                for (int n = 0; n < 4; n++)
                    acc[m][n] = __builtin_amdgcn_mfma_f32_16x16x32_bf16(af[m], bfr[n], acc[m][n], 0, 0, 0);
        }
    }

#pragma unroll
    for (int m = 0; m < 4; m++)
#pragma unroll
        for (int n = 0; n < 4; n++)
#pragma unroll
            for (int r = 0; r < 4; r++) {
                int row = bm + wr * 64 + m * 16 + hi * 4 + r;
                int col = bn + wc * 64 + n * 16 + lo;
                outF[(size_t)row * N + col] = acc[m][n][r] + bias[col];
            }
}

// ---------------- flash attention v12 ------------------------------------
// R7 grid/map/layouts verbatim; inner loop processes TWO KV tiles per
// iteration (32KB LDS): halves the sequential chain (32->16 iters for the
// longest block) and amortizes barrier/vmcnt/softmax-reduce overhead 2x.

static __device__ __forceinline__ u32x2 tr16(unsigned int addr) {
    u32x2 r;
    asm volatile("ds_read_b64_tr_b16 %0, %1" : "=v"(r) : "v"(addr));
    return r;
}

__global__ __launch_bounds__(256) void attn(
    const u16* __restrict__ Q,   // [B*H][N][64]
    const u16* __restrict__ Kg,
    const u16* __restrict__ Vg,
    u16* __restrict__ O)         // [B][N][H*64]
{
    // LDS bytes: K0 @0, K1 @8192, V0 @16384, V1 @24576 (32KB)
    __shared__ u16 lds[16384];
    const int t    = threadIdx.x;
    const int wid  = t >> 6, lane = t & 63;
    const int lo   = lane & 15, hi = lane >> 4;

    const int g    = blockIdx.x;             // 0..2047 (R7 map verbatim)
    const int slot = g >> 3;
    const int bh   = ((slot & 7) << 3) + (g & 7);
    const int a    = slot >> 3;
    const int u    = a >> 2, a0 = a & 3;
    const int qt   = 4 * u + ((u & 1) ? 3 - a0 : a0);

    const size_t base = (size_t)bh * SEQ * 64;
    const int qbase = qt * 64 + wid * 16;
    const unsigned ldsb = (unsigned)(uintptr_t)lds;

    // staging geometry (R7 verbatim, per 8KB tile)
    int srcK[2], srcV[2];
    unsigned dstK[2], dstV[2];
#pragma unroll
    for (int ti = 0; ti < 2; ti++) {
        int o   = t * 8 + ti * 2048;
        int row = o >> 6;
        int colb = ((o & 63) * 2) ^ ((row & 7) << 4);
        srcK[ti] = row * 64 + (colb >> 1);
        dstK[ti] = ldsb + o * 2;              // K0 region
        int st = o >> 9;
        int kv = (st >> 2) * 32 + ((o >> 4) & 31);
        int d  = (st & 3) * 16 + (o & 15);
        srcV[ti] = kv * 64 + d;
        dstV[ti] = ldsb + 16384u + o * 2;     // V0 region
    }

    // Q fragments (B-operand): lane holds Q[qbase+lo][h*32+hi*8+..] (pre-scaled)
    bf16x8 qf[2];
#pragma unroll
    for (int h = 0; h < 2; h++)
        qf[h] = *reinterpret_cast<const bf16x8*>(Q + base + (size_t)(qbase + lo) * 64 + h * 32 + hi * 8);
    asm volatile("" : "+v"(qf[0]), "+v"(qf[1]));

    float m_run = -3.0e38f, l_part = 0.f;
    f32x4 acc[4];
#pragma unroll
    for (int dt = 0; dt < 4; dt++) acc[dt] = (f32x4){0.f, 0.f, 0.f, 0.f};

    const int R = (qt + 2) >> 1;
    for (int r = 0; r < R; r++) {
        const int j0 = 2 * r;
        const bool h1 = (j0 + 1 <= qt);       // block-uniform
        __builtin_amdgcn_s_barrier();         // prev-iter readers done
        {
            const u16* Kt = Kg + base + (size_t)j0 * 4096;
            const u16* Vt = Vg + base + (size_t)j0 * 4096;
#pragma unroll
            for (int ti = 0; ti < 2; ti++) {
                gload16(Kt + srcK[ti], dstK[ti]);
                gload16(Vt + srcV[ti], dstV[ti]);
            }
            if (h1) {
#pragma unroll
                for (int ti = 0; ti < 2; ti++) {
                    gload16(Kt + 4096 + srcK[ti], dstK[ti] + 8192u);
                    gload16(Vt + 4096 + srcV[ti], dstV[ti] + 8192u);
                }
            }
        }
        asm volatile("s_waitcnt vmcnt(0)" ::: "memory");
        __builtin_amdgcn_s_barrier();
        __builtin_amdgcn_sched_barrier(0);

        // QK^T for both tiles: S[q=qbase+lo][kv = j*64 + kt*16 + hi*4 + rr]
        f32x4 s0[4], s1[4];
#pragma unroll
        for (int kh = 0; kh < 2; kh++) {
            bf16x8 kfa[2][2];
#pragma unroll
            for (int k2 = 0; k2 < 2; k2++)
#pragma unroll
                for (int h = 0; h < 2; h++)
                    kfa[k2][h] = *reinterpret_cast<const bf16x8*>(
                        (const char*)lds + ((kh * 2 + k2) * 16 + lo) * 128 + ((h * 64 + hi * 16) ^ ((lo & 7) << 4)));
            __builtin_amdgcn_s_setprio(1);
#pragma unroll
            for (int k2 = 0; k2 < 2; k2++) {
                f32x4 a2 = (f32x4){0.f, 0.f, 0.f, 0.f};
#pragma unroll
                for (int h = 0; h < 2; h++)
                    a2 = __builtin_amdgcn_mfma_f32_16x16x32_bf16(kfa[k2][h], qf[h], a2, 0, 0, 0);
                s0[kh * 2 + k2] = a2;
            }
            __builtin_amdgcn_s_setprio(0);
        }
        if (h1) {
#pragma unroll
            for (int kh = 0; kh < 2; kh++) {
                bf16x8 kfa[2][2];
#pragma unroll
                for (int k2 = 0; k2 < 2; k2++)
#pragma unroll
                    for (int h = 0; h < 2; h++)
                        kfa[k2][h] = *reinterpret_cast<const bf16x8*>(
                            (const char*)lds + 8192 + ((kh * 2 + k2) * 16 + lo) * 128 + ((h * 64 + hi * 16) ^ ((lo & 7) << 4)));
                __builtin_amdgcn_s_setprio(1);
#pragma unroll
                for (int k2 = 0; k2 < 2; k2++) {
                    f32x4 a2 = (f32x4){0.f, 0.f, 0.f, 0.f};
#pragma unroll
                    for (int h = 0; h < 2; h++)
                        a2 = __builtin_amdgcn_mfma_f32_16x16x32_bf16(kfa[k2][h], qf[h], a2, 0, 0, 0);
                    s1[kh * 2 + k2] = a2;
                }
                __builtin_amdgcn_s_setprio(0);
            }
        }
        // causal masks (diagonal tile only; local row index)
        const int ql = wid * 16 + lo;
        if (j0 == qt) {
#pragma unroll
            for (int kt = 0; kt < 4; kt++)
#pragma unroll
                for (int rr = 0; rr < 4; rr++)
                    if (kt * 16 + hi * 4 + rr > ql) s0[kt][rr] = -1.0e30f;
        }
        if (h1 && j0 + 1 == qt) {
#pragma unroll
            for (int kt = 0; kt < 4; kt++)
#pragma unroll
                for (int rr = 0; rr < 4; rr++)
                    if (kt * 16 + hi * 4 + rr > ql) s1[kt][rr] = -1.0e30f;
        }
        // joint online softmax over up to 128 kv (log2 domain), defer-max THR=8
        float vm = s0[0][0];
#pragma unroll
        for (int kt = 0; kt < 4; kt++)
#pragma unroll
            for (int rr = 0; rr < 4; rr++) vm = fmaxf(vm, s0[kt][rr]);
        if (h1) {
#pragma unroll
            for (int kt = 0; kt < 4; kt++)
#pragma unroll
                for (int rr = 0; rr < 4; rr++) vm = fmaxf(vm, s1[kt][rr]);
        }
        vm = fmaxf(vm, __shfl_xor(vm, 16));
        vm = fmaxf(vm, __shfl_xor(vm, 32));
        if (!__all(vm <= m_run + 8.0f)) {
            float nm = fmaxf(m_run, vm);
            float sc = exp2f(m_run - nm);
            m_run = nm;
            l_part *= sc;
#pragma unroll
            for (int dt = 0; dt < 4; dt++)
#pragma unroll
                for (int rr = 0; rr < 4; rr++) acc[dt][rr] *= sc;   // cols=q=lo: lane-local
        }
        float ps = 0.f;
#pragma unroll
        for (int kt = 0; kt < 4; kt++)
#pragma unroll
            for (int rr = 0; rr < 4; rr++) {
                float p = exp2f(s0[kt][rr] - m_run);
                s0[kt][rr] = p;
                ps += p;
            }
        bf16x8 pa0[2];
        {
            union { u16 uu[8]; bf16x8 v; } q0, q1;
#pragma unroll
            for (int e = 0; e < 4; e++) {
                q0.uu[e]     = f2bf(s0[0][e]);
                q0.uu[4 + e] = f2bf(s0[1][e]);
                q1.uu[e]     = f2bf(s0[2][e]);
                q1.uu[4 + e] = f2bf(s0[3][e]);
            }
            pa0[0] = q0.v;
            pa0[1] = q1.v;
        }
        bf16x8 pa1[2];
        if (h1) {
#pragma unroll
            for (int kt = 0; kt < 4; kt++)
#pragma unroll
                for (int rr = 0; rr < 4; rr++) {
                    float p = exp2f(s1[kt][rr] - m_run);
                    s1[kt][rr] = p;
                    ps += p;
                }
            union { u16 uu[8]; bf16x8 v; } q0, q1;
#pragma unroll
            for (int e = 0; e < 4; e++) {
                q0.uu[e]     = f2bf(s1[0][e]);
                q0.uu[4 + e] = f2bf(s1[1][e]);
                q1.uu[e]     = f2bf(s1[2][e]);
                q1.uu[4 + e] = f2bf(s1[3][e]);
            }
            pa1[0] = q0.v;
            pa1[1] = q1.v;
        }
        l_part += ps;

        // PV both tiles: acc[dt] = mfma(A=V^T frag, B=P) -> C[row=d][col=q=lo]
        const unsigned vtb = ldsb + 16384u + (unsigned)((hi * 64 + lo * 4) * 2);
#pragma unroll
        for (int pr = 0; pr < 2; pr++) {
            u32x2 tv[2][2][2];
#pragma unroll
            for (int d2 = 0; d2 < 2; d2++)
#pragma unroll
                for (int h = 0; h < 2; h++)
#pragma unroll
                    for (int sel = 0; sel < 2; sel++)
                        tv[d2][h][sel] = tr16(vtb + (unsigned)(((h * 4 + pr * 2 + d2) * 512 + sel * 256) * 2));
            asm volatile("s_waitcnt lgkmcnt(0)" ::: "memory");
            __builtin_amdgcn_sched_barrier(0);
            __builtin_amdgcn_s_setprio(1);
#pragma unroll
            for (int d2 = 0; d2 < 2; d2++) {
#pragma unroll
                for (int h = 0; h < 2; h++) {
                    union { unsigned int w[4]; bf16x8 v; } bv;
                    bv.w[0] = tv[d2][h][0][0];
                    bv.w[1] = tv[d2][h][0][1];
                    bv.w[2] = tv[d2][h][1][0];
                    bv.w[3] = tv[d2][h][1][1];
                    acc[pr * 2 + d2] = __builtin_amdgcn_mfma_f32_16x16x32_bf16(bv.v, pa0[h], acc[pr * 2 + d2], 0, 0, 0);
                }
            }
            __builtin_amdgcn_s_setprio(0);
        }
        if (h1) {
            const unsigned vtb1 = vtb + 8192u;
#pragma unroll
            for (int pr = 0; pr < 2; pr++) {
                u32x2 tv[2][2][2];
#pragma unroll
                for (int d2 = 0; d2 < 2; d2++)
#pragma unroll
                    for (int h = 0; h < 2; h++)
#pragma unroll
                        for (int sel = 0; sel < 2; sel++)
                            tv[d2][h][sel] = tr16(vtb1 + (unsigned)(((h * 4 + pr * 2 + d2) * 512 + sel * 256) * 2));
                asm volatile("s_waitcnt lgkmcnt(0)" ::: "memory");
                __builtin_amdgcn_sched_barrier(0);
                __builtin_amdgcn_s_setprio(1);
#pragma unroll
                for (int d2 = 0; d2 < 2; d2++) {
#pragma unroll
                    for (int h = 0; h < 2; h++) {
                        union { unsigned int w[4]; bf16x8 v; } bv;
                        bv.w[0] = tv[d2][h][0][0];
                        bv.w[1] = tv[d2][h][0][1];
                        bv.w[2] = tv[d2][h][1][0];
                        bv.w[3] = tv[d2][h][1][1];
                        acc[pr * 2 + d2] = __builtin_amdgcn_mfma_f32_16x16x32_bf16(bv.v, pa1[h], acc[pr * 2 + d2], 0, 0, 0);
                    }
                }
                __builtin_amdgcn_s_setprio(0);
            }
        }
    }

    // epilogue (R7 verbatim): finish l across lane groups, direct stores
    float l = l_part;
    l += __shfl_xor(l, 16);
    l += __shfl_xor(l, 32);
    const float inv = 1.0f / l;
    const int b = bh >> 4, hh = bh & 15;
    const size_t orow = ((size_t)(b * SEQ + qbase + lo)) * 1024 + hh * 64;
#pragma unroll
    for (int dt = 0; dt < 4; dt++) {
        union { u16 uu[4]; uint2 d2; } pk;
#pragma unroll
        for (int rr = 0; rr < 4; rr++) pk.uu[rr] = f2bf(acc[dt][rr] * inv);
        *reinterpret_cast<uint2*>(O + orow + dt * 16 + hi * 4) = pk.d2;
    }
}

extern "C" void kernel_launch(void* const* d_in, const int* in_sizes, int n_in,
                              void* d_out, int out_size, void* d_ws, size_t ws_size,
                              hipStream_t stream) {
    const float* x  = (const float*)d_in[0];
    const float* Wq = (const float*)d_in[1];
    const float* Wk = (const float*)d_in[2];
    const float* Wv = (const float*)d_in[3];
    const float* Wo = (const float*)d_in[4];
    const float* bo = (const float*)d_in[5];
    float* out = (float*)d_out;

    char* ws = (char*)d_ws;
    u16* xb  = (u16*)ws;                              // 16 MiB, then weights contiguous
    u16* wqb = (u16*)(ws + 16777216);
    u16* wkb = wqb + 1048576;
    u16* wvb = wkb + 1048576;
    u16* wob = wvb + 1048576;
    u16* q   = (u16*)(ws + 16777216 + 8388608);       // [B][H][N][D] bf16
    u16* k   = q + 8388608;
    u16* v   = k + 8388608;
    u16* ao  = v + 8388608;                           // [B][N][H*64] bf16

    castk_all<<<3072, 256, 0, stream>>>(x, Wq, Wk, Wv, Wo, xb);

    gemm_qkv<<<dim3(ROWS / BM, 24), 256, 0, stream>>>(xb, wqb, wkb, wvb, q, k, v);

    attn<<<2048, 256, 0, stream>>>(q, k, v, ao);

    gemm_out<<<dim3(ROWS / BM, MODEL_DIM / BN), 256, 0, stream>>>(ao, wob, out, bo);
}

// Round 13
// 175.015 us; speedup vs baseline: 1.6774x; 1.0987x over previous
//
#include <hip/hip_runtime.h>
#include <hip/hip_bf16.h>

typedef unsigned short u16;
typedef __attribute__((ext_vector_type(8))) __bf16 bf16x8;
typedef __attribute__((ext_vector_type(4))) float f32x4;
typedef __attribute__((ext_vector_type(2))) unsigned int u32x2;

#define MODEL_DIM 1024
#define NUM_HEADS 16
#define HEAD_DIM  64
#define BATCH     4
#define SEQ       2048
#define ROWS      (BATCH*SEQ)     // 8192

static __device__ __forceinline__ u16 f2bf(float f) {
    union { __hip_bfloat16 h; u16 u; } cv;
    cv.h = __float2bfloat16(f);
    return cv.u;
}

static __device__ __forceinline__ void gload16(const u16* g, unsigned lds_byte) {
    __builtin_amdgcn_global_load_lds(
        (const __attribute__((address_space(1))) unsigned int*)g,
        (__attribute__((address_space(3))) unsigned int*)(uintptr_t)lds_byte,
        16, 0, 0);
}

// ---------------- fused cast f32 -> bf16 (x + 4 weights, contiguous out) ----
__global__ void castk_all(const float* __restrict__ x,
                          const float* __restrict__ w0, const float* __restrict__ w1,
                          const float* __restrict__ w2, const float* __restrict__ w3,
                          u16* __restrict__ out) {
    const int total = ROWS * MODEL_DIM + 4 * MODEL_DIM * MODEL_DIM;  // 12.58M
    int i = (blockIdx.x * blockDim.x + threadIdx.x) * 4;
    int stride = gridDim.x * blockDim.x * 4;
    for (; i < total; i += stride) {
        const float* src;
        int off;
        if (i < ROWS * MODEL_DIM) { src = x; off = i; }
        else {
            int j = i - ROWS * MODEL_DIM;
            int w = j >> 20;
            off = j & 1048575;
            src = (w == 0) ? w0 : (w == 1) ? w1 : (w == 2) ? w2 : w3;
        }
        float4 v = *reinterpret_cast<const float4*>(src + off);
        ushort4 o;
        o.x = f2bf(v.x); o.y = f2bf(v.y); o.z = f2bf(v.z); o.w = f2bf(v.w);
        *reinterpret_cast<ushort4*>(out + i) = o;
    }
}

// ---------------- pipelined NT GEMM: 256x128 tile, dbuf + counted vmcnt ----
// 512 threads = 8 waves (4 M-waves x 2 N-waves), per-wave 64x64 output.
// Per K-step: stage next tile (6 gload_lds) BEFORE vmcnt(6) -> prefetch spans
// the whole compute; raw s_barriers (no implicit vmcnt(0) drain).

static __device__ __forceinline__ bf16x8 frag_read(const char* base, int row, int h,
                                                   int lo, int hi) {
    return *reinterpret_cast<const bf16x8*>(
        base + row * 128 + ((h * 64 + hi * 16) ^ ((lo & 7) << 4)));
}

template<int EPI>
__global__ __launch_bounds__(512, 2) void gemm_pipe(
    const u16* __restrict__ A,
    const u16* __restrict__ Wq, const u16* __restrict__ Wk, const u16* __restrict__ Wv,
    u16* __restrict__ qO, u16* __restrict__ kO, u16* __restrict__ vO,
    float* __restrict__ outF, const float* __restrict__ bias)
{
    __shared__ u16 As[2 * 16384];    // 2 x 32KB (256 rows x 64 cols)
    __shared__ u16 Bs[2 * 8192];     // 2 x 16KB (128 rows x 64 cols)
    const int t    = threadIdx.x;
    const int wid  = t >> 6;
    const int lane = t & 63;
    const int lo   = lane & 15, hi = lane >> 4;
    const int bm   = blockIdx.x * 256;
    int mat, bn;
    const u16* W;
    u16* outB = nullptr;
    float qscale = 1.0f;
    if (EPI == 0) {
        mat = blockIdx.y >> 3;
        bn  = (blockIdx.y & 7) * 128;
        W   = (mat == 0) ? Wq : (mat == 1) ? Wk : Wv;
        outB = (mat == 0) ? qO : (mat == 1) ? kO : vO;
        qscale = (mat == 0) ? 0.18033688f : 1.0f;   // 0.125*log2(e)
    } else {
        bn = blockIdx.y * 128;
        W  = Wq;                      // Wo passed in slot 0
    }
    const int wr = wid >> 1, wc = wid & 1;
    const int K = MODEL_DIM;
    const unsigned AsB = (unsigned)(uintptr_t)As;
    const unsigned BsB = (unsigned)(uintptr_t)Bs;

    // per-thread staging geometry (verified swizzle: colb = 2(o&63) ^ ((row&7)<<4))
    const u16* aSrc[4]; unsigned aDst[4];
    const u16* bSrc[2]; unsigned bDst[2];
#pragma unroll
    for (int ti = 0; ti < 4; ti++) {
        int o = t * 8 + ti * 4096;
        int row = o >> 6;
        int colb = ((o & 63) * 2) ^ ((row & 7) << 4);
        aSrc[ti] = A + (size_t)(bm + row) * K + (colb >> 1);
        aDst[ti] = (unsigned)(o * 2);
    }
#pragma unroll
    for (int ti = 0; ti < 2; ti++) {
        int o = t * 8 + ti * 4096;
        int row = o >> 6;
        int colb = ((o & 63) * 2) ^ ((row & 7) << 4);
        bSrc[ti] = W + (size_t)(bn + row) * K + (colb >> 1);
        bDst[ti] = (unsigned)(o * 2);
    }

    f32x4 acc[4][4];
#pragma unroll
    for (int m = 0; m < 4; m++)
#pragma unroll
        for (int n = 0; n < 4; n++) acc[m][n] = (f32x4){0.f, 0.f, 0.f, 0.f};

    // prologue: stage K-tile 0 into buffer 0
#pragma unroll
    for (int ti = 0; ti < 4; ti++) gload16(aSrc[ti], AsB + aDst[ti]);
#pragma unroll
    for (int ti = 0; ti < 2; ti++) gload16(bSrc[ti], BsB + bDst[ti]);

    for (int kt = 0; kt < 16; kt++) {
        const int p = kt & 1;
        if (kt < 15) {
            const int ko = (kt + 1) * 64;
            const unsigned pa = (unsigned)((p ^ 1) * 32768);
            const unsigned pb = (unsigned)((p ^ 1) * 16384);
#pragma unroll
            for (int ti = 0; ti < 4; ti++) gload16(aSrc[ti] + ko, AsB + pa + aDst[ti]);
#pragma unroll
            for (int ti = 0; ti < 2; ti++) gload16(bSrc[ti] + ko, BsB + pb + bDst[ti]);
            asm volatile("s_waitcnt vmcnt(6)" ::: "memory");  // tile kt landed; kt+1 in flight
        } else {
            asm volatile("s_waitcnt vmcnt(0)" ::: "memory");
        }
        __builtin_amdgcn_s_barrier();
        __builtin_amdgcn_sched_barrier(0);

        const char* Ab = (const char*)As + p * 32768;
        const char* Bb = (const char*)Bs + p * 16384;
#pragma unroll
        for (int kk = 0; kk < 2; kk++) {
            bf16x8 bfr[4];
#pragma unroll
            for (int n = 0; n < 4; n++)
                bfr[n] = frag_read(Bb, wc * 64 + n * 16 + lo, kk, lo, hi);
#pragma unroll
            for (int mh = 0; mh < 2; mh++) {
                bf16x8 af[2];
#pragma unroll
                for (int m2 = 0; m2 < 2; m2++)
                    af[m2] = frag_read(Ab, wr * 64 + (mh * 2 + m2) * 16 + lo, kk, lo, hi);
                __builtin_amdgcn_s_setprio(1);
#pragma unroll
                for (int m2 = 0; m2 < 2; m2++)
#pragma unroll
                    for (int n = 0; n < 4; n++)
                        acc[mh * 2 + m2][n] = __builtin_amdgcn_mfma_f32_16x16x32_bf16(af[m2], bfr[n], acc[mh * 2 + m2][n], 0, 0, 0);
                __builtin_amdgcn_s_setprio(0);
                __builtin_amdgcn_s_barrier();   // phase lockstep; final one guards buf reuse
            }
        }
    }

#pragma unroll
    for (int m = 0; m < 4; m++)
#pragma unroll
        for (int n = 0; n < 4; n++)
#pragma unroll
            for (int r = 0; r < 4; r++) {
                int row = bm + wr * 64 + m * 16 + hi * 4 + r;
                int col = bn + wc * 64 + n * 16 + lo;
                if (EPI == 0) {
                    int b = row >> 11, np = row & 2047;
                    int hh = col >> 6, dd = col & 63;
                    outB[(((size_t)(b * NUM_HEADS + hh) * SEQ + np) << 6) + dd] = f2bf(acc[m][n][r] * qscale);
                } else {
                    outF[(size_t)row * MODEL_DIM + col] = acc[m][n][r] + bias[col];
                }
            }
}

// ---------------- flash attention v13: R7 body + dbuf counted-vmcnt --------
// R7 grid/map/layouts/softmax verbatim; 32KB LDS double buffer; stage j+1
// before vmcnt(4) so the staging latency leaves the critical path.

static __device__ __forceinline__ u32x2 tr16(unsigned int addr) {
    u32x2 r;
    asm volatile("ds_read_b64_tr_b16 %0, %1" : "=v"(r) : "v"(addr));
    return r;
}

__global__ __launch_bounds__(256, 5) void attn(
    const u16* __restrict__ Q,   // [B*H][N][64]
    const u16* __restrict__ Kg,
    const u16* __restrict__ Vg,
    u16* __restrict__ O)         // [B][N][H*64]
{
    // LDS bytes: buffer p at p*16384: K swizzled @+0 (8KB), V subtiled @+8192
    __shared__ u16 lds[16384];
    const int t    = threadIdx.x;
    const int wid  = t >> 6, lane = t & 63;
    const int lo   = lane & 15, hi = lane >> 4;

    const int g    = blockIdx.x;             // 0..2047 (R7 map verbatim)
    const int slot = g >> 3;
    const int bh   = ((slot & 7) << 3) + (g & 7);
    const int a    = slot >> 3;
    const int u    = a >> 2, a0 = a & 3;
    const int qt   = 4 * u + ((u & 1) ? 3 - a0 : a0);

    const size_t base = (size_t)bh * SEQ * 64;
    const int qbase = qt * 64 + wid * 16;
    const unsigned ldsb = (unsigned)(uintptr_t)lds;

    // staging geometry (R7 verbatim)
    int srcK[2], srcV[2];
    unsigned dstK[2], dstV[2];
#pragma unroll
    for (int ti = 0; ti < 2; ti++) {
        int o   = t * 8 + ti * 2048;
        int row = o >> 6;
        int colb = ((o & 63) * 2) ^ ((row & 7) << 4);
        srcK[ti] = row * 64 + (colb >> 1);
        dstK[ti] = ldsb + o * 2;
        int st = o >> 9;
        int kv = (st >> 2) * 32 + ((o >> 4) & 31);
        int d  = (st & 3) * 16 + (o & 15);
        srcV[ti] = kv * 64 + d;
        dstV[ti] = ldsb + 8192u + o * 2;
    }

    // Q fragments (B-operand): lane holds Q[qbase+lo][h*32+hi*8+..] (pre-scaled)
    bf16x8 qf[2];
#pragma unroll
    for (int h = 0; h < 2; h++)
        qf[h] = *reinterpret_cast<const bf16x8*>(Q + base + (size_t)(qbase + lo) * 64 + h * 32 + hi * 8);
    asm volatile("" : "+v"(qf[0]), "+v"(qf[1]));

    float m_run = -3.0e38f, l_part = 0.f;
    f32x4 acc[4];
#pragma unroll
    for (int dt = 0; dt < 4; dt++) acc[dt] = (f32x4){0.f, 0.f, 0.f, 0.f};

    // prologue: stage tile 0 -> buffer 0
    {
        const u16* Kt = Kg + base;
        const u16* Vt = Vg + base;
#pragma unroll
        for (int ti = 0; ti < 2; ti++) {
            gload16(Kt + srcK[ti], dstK[ti]);
            gload16(Vt + srcV[ti], dstV[ti]);
        }
    }

    for (int j = 0; j <= qt; j++) {
        const int p = j & 1;
        if (j < qt) {
            const u16* Kt = Kg + base + (size_t)(j + 1) * 4096;
            const u16* Vt = Vg + base + (size_t)(j + 1) * 4096;
            const unsigned bs = (unsigned)((p ^ 1) * 16384);
#pragma unroll
            for (int ti = 0; ti < 2; ti++) {
                gload16(Kt + srcK[ti], dstK[ti] + bs);
                gload16(Vt + srcV[ti], dstV[ti] + bs);
            }
            asm volatile("s_waitcnt vmcnt(4)" ::: "memory");   // tile j landed; j+1 in flight
        } else {
            asm volatile("s_waitcnt vmcnt(0)" ::: "memory");
        }
        __builtin_amdgcn_s_barrier();
        __builtin_amdgcn_sched_barrier(0);

        const char* Kcur = (const char*)lds + p * 16384;
        // S^T = K Q^T: lane holds S[q=qbase+lo][kv=j*64+kt*16+hi*4+r]
        f32x4 s[4];
#pragma unroll
        for (int kh = 0; kh < 2; kh++) {
            bf16x8 kfa[2][2];
#pragma unroll
            for (int k2 = 0; k2 < 2; k2++)
#pragma unroll
                for (int h = 0; h < 2; h++)
                    kfa[k2][h] = *reinterpret_cast<const bf16x8*>(
                        Kcur + ((kh * 2 + k2) * 16 + lo) * 128 + ((h * 64 + hi * 16) ^ ((lo & 7) << 4)));
            __builtin_amdgcn_s_setprio(1);
#pragma unroll
            for (int k2 = 0; k2 < 2; k2++) {
                f32x4 a2 = (f32x4){0.f, 0.f, 0.f, 0.f};
#pragma unroll
                for (int h = 0; h < 2; h++)
                    a2 = __builtin_amdgcn_mfma_f32_16x16x32_bf16(kfa[k2][h], qf[h], a2, 0, 0, 0);
                s[kh * 2 + k2] = a2;
            }
            __builtin_amdgcn_s_setprio(0);
        }
        if (j == qt) {                       // diagonal: causal mask (local indices)
            const int ql = wid * 16 + lo;
#pragma unroll
            for (int kt = 0; kt < 4; kt++)
#pragma unroll
                for (int r = 0; r < 4; r++)
                    if (kt * 16 + hi * 4 + r > ql) s[kt][r] = -1.0e30f;
        }
        // online softmax (log2 domain, Q pre-scaled), defer-max THR=8
        float vm = s[0][0];
#pragma unroll
        for (int kt = 0; kt < 4; kt++)
#pragma unroll
            for (int r = 0; r < 4; r++) vm = fmaxf(vm, s[kt][r]);
        vm = fmaxf(vm, __shfl_xor(vm, 16));
        vm = fmaxf(vm, __shfl_xor(vm, 32));
        if (!__all(vm <= m_run + 8.0f)) {
            float nm = fmaxf(m_run, vm);
            float sc = exp2f(m_run - nm);
            m_run = nm;
            l_part *= sc;
#pragma unroll
            for (int dt = 0; dt < 4; dt++)
#pragma unroll
                for (int r = 0; r < 4; r++) acc[dt][r] *= sc;   // cols=q=lo: lane-local
        }
        float ps = 0.f;
#pragma unroll
        for (int kt = 0; kt < 4; kt++)
#pragma unroll
            for (int r = 0; r < 4; r++) {
                float pv = exp2f(s[kt][r] - m_run);
                s[kt][r] = pv;
                ps += pv;
            }
        l_part += ps;
        // pack P into PV B-fragments (kappa: e<4 -> kv=4hi+e; e>=4 -> 16+4hi+(e-4))
        bf16x8 pa[2];
        {
            union { u16 uu[8]; bf16x8 v; } q0, q1;
#pragma unroll
            for (int e = 0; e < 4; e++) {
                q0.uu[e]     = f2bf(s[0][e]);
                q0.uu[4 + e] = f2bf(s[1][e]);
                q1.uu[e]     = f2bf(s[2][e]);
                q1.uu[4 + e] = f2bf(s[3][e]);
            }
            pa[0] = q0.v;
            pa[1] = q1.v;
        }

        // PV swapped: acc[dt] = mfma(A=V^T frag, B=P) -> C[row=d][col=q=lo]
        const unsigned vtb = ldsb + (unsigned)(p * 16384) + 8192u + (unsigned)((hi * 64 + lo * 4) * 2);
#pragma unroll
        for (int pr = 0; pr < 2; pr++) {
            u32x2 tv[2][2][2];
#pragma unroll
            for (int d2 = 0; d2 < 2; d2++)
#pragma unroll
                for (int h = 0; h < 2; h++)
#pragma unroll
                    for (int sel = 0; sel < 2; sel++)
                        tv[d2][h][sel] = tr16(vtb + (unsigned)(((h * 4 + pr * 2 + d2) * 512 + sel * 256) * 2));
            asm volatile("s_waitcnt lgkmcnt(0)" ::: "memory");
            __builtin_amdgcn_sched_barrier(0);
            __builtin_amdgcn_s_setprio(1);
#pragma unroll
            for (int d2 = 0; d2 < 2; d2++) {
#pragma unroll
                for (int h = 0; h < 2; h++) {
                    union { unsigned int w[4]; bf16x8 v; } bv;
                    bv.w[0] = tv[d2][h][0][0];
                    bv.w[1] = tv[d2][h][0][1];
                    bv.w[2] = tv[d2][h][1][0];
                    bv.w[3] = tv[d2][h][1][1];
                    acc[pr * 2 + d2] = __builtin_amdgcn_mfma_f32_16x16x32_bf16(bv.v, pa[h], acc[pr * 2 + d2], 0, 0, 0);
                }
            }
            __builtin_amdgcn_s_setprio(0);
        }
        __builtin_amdgcn_s_barrier();        // all waves done reading buffer p
    }

    // epilogue (R7 verbatim)
    float l = l_part;
    l += __shfl_xor(l, 16);
    l += __shfl_xor(l, 32);
    const float inv = 1.0f / l;
    const int b = bh >> 4, hh = bh & 15;
    const size_t orow = ((size_t)(b * SEQ + qbase + lo)) * 1024 + hh * 64;
#pragma unroll
    for (int dt = 0; dt < 4; dt++) {
        union { u16 uu[4]; uint2 d2; } pk;
#pragma unroll
        for (int r = 0; r < 4; r++) pk.uu[r] = f2bf(acc[dt][r] * inv);
        *reinterpret_cast<uint2*>(O + orow + dt * 16 + hi * 4) = pk.d2;
    }
}

extern "C" void kernel_launch(void* const* d_in, const int* in_sizes, int n_in,
                              void* d_out, int out_size, void* d_ws, size_t ws_size,
                              hipStream_t stream) {
    const float* x  = (const float*)d_in[0];
    const float* Wq = (const float*)d_in[1];
    const float* Wk = (const float*)d_in[2];
    const float* Wv = (const float*)d_in[3];
    const float* Wo = (const float*)d_in[4];
    const float* bo = (const float*)d_in[5];
    float* out = (float*)d_out;

    char* ws = (char*)d_ws;
    u16* xb  = (u16*)ws;                              // 16 MiB, then weights contiguous
    u16* wqb = (u16*)(ws + 16777216);
    u16* wkb = wqb + 1048576;
    u16* wvb = wkb + 1048576;
    u16* wob = wvb + 1048576;
    u16* q   = (u16*)(ws + 16777216 + 8388608);       // [B][H][N][D] bf16
    u16* k   = q + 8388608;
    u16* v   = k + 8388608;
    u16* ao  = v + 8388608;                           // [B][N][H*64] bf16

    castk_all<<<3072, 256, 0, stream>>>(x, Wq, Wk, Wv, Wo, xb);

    gemm_pipe<0><<<dim3(ROWS / 256, 24), 512, 0, stream>>>(
        xb, wqb, wkb, wvb, q, k, v, nullptr, nullptr);

    attn<<<2048, 256, 0, stream>>>(q, k, v, ao);

    gemm_pipe<1><<<dim3(ROWS / 256, MODEL_DIM / 128), 512, 0, stream>>>(
        ao, wob, nullptr, nullptr, nullptr, nullptr, nullptr, out, bo);
}

// Round 14
// 164.404 us; speedup vs baseline: 1.7857x; 1.0645x over previous
//
#include <hip/hip_runtime.h>
#include <hip/hip_bf16.h>

typedef unsigned short u16;
typedef __attribute__((ext_vector_type(8))) __bf16 bf16x8;
typedef __attribute__((ext_vector_type(4))) float f32x4;
typedef __attribute__((ext_vector_type(2))) unsigned int u32x2;

#define MODEL_DIM 1024
#define NUM_HEADS 16
#define HEAD_DIM  64
#define BATCH     4
#define SEQ       2048
#define ROWS      (BATCH*SEQ)     // 8192

static __device__ __forceinline__ u16 f2bf(float f) {
    union { __hip_bfloat16 h; u16 u; } cv;
    cv.h = __float2bfloat16(f);
    return cv.u;
}

static __device__ __forceinline__ void gload16(const u16* g, unsigned lds_byte) {
    __builtin_amdgcn_global_load_lds(
        (const __attribute__((address_space(1))) unsigned int*)g,
        (__attribute__((address_space(3))) unsigned int*)(uintptr_t)lds_byte,
        16, 0, 0);
}

// ---------------- fused cast f32 -> bf16 (x + 4 weights, contiguous out) ----
__global__ void castk_all(const float* __restrict__ x,
                          const float* __restrict__ w0, const float* __restrict__ w1,
                          const float* __restrict__ w2, const float* __restrict__ w3,
                          u16* __restrict__ out) {
    const int total = ROWS * MODEL_DIM + 4 * MODEL_DIM * MODEL_DIM;  // 12.58M
    int i = (blockIdx.x * blockDim.x + threadIdx.x) * 4;
    int stride = gridDim.x * blockDim.x * 4;
    for (; i < total; i += stride) {
        const float* src;
        int off;
        if (i < ROWS * MODEL_DIM) { src = x; off = i; }
        else {
            int j = i - ROWS * MODEL_DIM;
            int w = j >> 20;
            off = j & 1048575;
            src = (w == 0) ? w0 : (w == 1) ? w1 : (w == 2) ? w2 : w3;
        }
        float4 v = *reinterpret_cast<const float4*>(src + off);
        ushort4 o;
        o.x = f2bf(v.x); o.y = f2bf(v.y); o.z = f2bf(v.z); o.w = f2bf(v.w);
        *reinterpret_cast<ushort4*>(out + i) = o;
    }
}

// ---------------- pipelined NT GEMM: 256x128 tile, dbuf + counted vmcnt ----
// (R13 verbatim — passed, keep)

static __device__ __forceinline__ bf16x8 frag_read(const char* base, int row, int h,
                                                   int lo, int hi) {
    return *reinterpret_cast<const bf16x8*>(
        base + row * 128 + ((h * 64 + hi * 16) ^ ((lo & 7) << 4)));
}

template<int EPI>
__global__ __launch_bounds__(512, 2) void gemm_pipe(
    const u16* __restrict__ A,
    const u16* __restrict__ Wq, const u16* __restrict__ Wk, const u16* __restrict__ Wv,
    u16* __restrict__ qO, u16* __restrict__ kO, u16* __restrict__ vO,
    float* __restrict__ outF, const float* __restrict__ bias)
{
    __shared__ u16 As[2 * 16384];    // 2 x 32KB (256 rows x 64 cols)
    __shared__ u16 Bs[2 * 8192];     // 2 x 16KB (128 rows x 64 cols)
    const int t    = threadIdx.x;
    const int wid  = t >> 6;
    const int lane = t & 63;
    const int lo   = lane & 15, hi = lane >> 4;
    const int bm   = blockIdx.x * 256;
    int mat, bn;
    const u16* W;
    u16* outB = nullptr;
    float qscale = 1.0f;
    if (EPI == 0) {
        mat = blockIdx.y >> 3;
        bn  = (blockIdx.y & 7) * 128;
        W   = (mat == 0) ? Wq : (mat == 1) ? Wk : Wv;
        outB = (mat == 0) ? qO : (mat == 1) ? kO : vO;
        qscale = (mat == 0) ? 0.18033688f : 1.0f;   // 0.125*log2(e)
    } else {
        bn = blockIdx.y * 128;
        W  = Wq;                      // Wo passed in slot 0
    }
    const int wr = wid >> 1, wc = wid & 1;
    const int K = MODEL_DIM;
    const unsigned AsB = (unsigned)(uintptr_t)As;
    const unsigned BsB = (unsigned)(uintptr_t)Bs;

    const u16* aSrc[4]; unsigned aDst[4];
    const u16* bSrc[2]; unsigned bDst[2];
#pragma unroll
    for (int ti = 0; ti < 4; ti++) {
        int o = t * 8 + ti * 4096;
        int row = o >> 6;
        int colb = ((o & 63) * 2) ^ ((row & 7) << 4);
        aSrc[ti] = A + (size_t)(bm + row) * K + (colb >> 1);
        aDst[ti] = (unsigned)(o * 2);
    }
#pragma unroll
    for (int ti = 0; ti < 2; ti++) {
        int o = t * 8 + ti * 4096;
        int row = o >> 6;
        int colb = ((o & 63) * 2) ^ ((row & 7) << 4);
        bSrc[ti] = W + (size_t)(bn + row) * K + (colb >> 1);
        bDst[ti] = (unsigned)(o * 2);
    }

    f32x4 acc[4][4];
#pragma unroll
    for (int m = 0; m < 4; m++)
#pragma unroll
        for (int n = 0; n < 4; n++) acc[m][n] = (f32x4){0.f, 0.f, 0.f, 0.f};

#pragma unroll
    for (int ti = 0; ti < 4; ti++) gload16(aSrc[ti], AsB + aDst[ti]);
#pragma unroll
    for (int ti = 0; ti < 2; ti++) gload16(bSrc[ti], BsB + bDst[ti]);

    for (int kt = 0; kt < 16; kt++) {
        const int p = kt & 1;
        if (kt < 15) {
            const int ko = (kt + 1) * 64;
            const unsigned pa = (unsigned)((p ^ 1) * 32768);
            const unsigned pb = (unsigned)((p ^ 1) * 16384);
#pragma unroll
            for (int ti = 0; ti < 4; ti++) gload16(aSrc[ti] + ko, AsB + pa + aDst[ti]);
#pragma unroll
            for (int ti = 0; ti < 2; ti++) gload16(bSrc[ti] + ko, BsB + pb + bDst[ti]);
            asm volatile("s_waitcnt vmcnt(6)" ::: "memory");
        } else {
            asm volatile("s_waitcnt vmcnt(0)" ::: "memory");
        }
        __builtin_amdgcn_s_barrier();
        __builtin_amdgcn_sched_barrier(0);

        const char* Ab = (const char*)As + p * 32768;
        const char* Bb = (const char*)Bs + p * 16384;
#pragma unroll
        for (int kk = 0; kk < 2; kk++) {
            bf16x8 bfr[4];
#pragma unroll
            for (int n = 0; n < 4; n++)
                bfr[n] = frag_read(Bb, wc * 64 + n * 16 + lo, kk, lo, hi);
#pragma unroll
            for (int mh = 0; mh < 2; mh++) {
                bf16x8 af[2];
#pragma unroll
                for (int m2 = 0; m2 < 2; m2++)
                    af[m2] = frag_read(Ab, wr * 64 + (mh * 2 + m2) * 16 + lo, kk, lo, hi);
                __builtin_amdgcn_s_setprio(1);
#pragma unroll
                for (int m2 = 0; m2 < 2; m2++)
#pragma unroll
                    for (int n = 0; n < 4; n++)
                        acc[mh * 2 + m2][n] = __builtin_amdgcn_mfma_f32_16x16x32_bf16(af[m2], bfr[n], acc[mh * 2 + m2][n], 0, 0, 0);
                __builtin_amdgcn_s_setprio(0);
                __builtin_amdgcn_s_barrier();
            }
        }
    }

#pragma unroll
    for (int m = 0; m < 4; m++)
#pragma unroll
        for (int n = 0; n < 4; n++)
#pragma unroll
            for (int r = 0; r < 4; r++) {
                int row = bm + wr * 64 + m * 16 + hi * 4 + r;
                int col = bn + wc * 64 + n * 16 + lo;
                if (EPI == 0) {
                    int b = row >> 11, np = row & 2047;
                    int hh = col >> 6, dd = col & 63;
                    outB[(((size_t)(b * NUM_HEADS + hh) * SEQ + np) << 6) + dd] = f2bf(acc[m][n][r] * qscale);
                } else {
                    outF[(size_t)row * MODEL_DIM + col] = acc[m][n][r] + bias[col];
                }
            }
}

// ---------------- flash attention v14 ------------------------------------
// R13 core with: V single-buffer (24KB LDS -> 6 blocks/CU), l-sum via MFMA
// (ones-fragment; no per-iter adds, no epilogue shuffles), loop-invariant
// tr16 base (addresses hoisted by LICM), longest-first per-CU qt order.

static __device__ __forceinline__ u32x2 tr16(unsigned int addr) {
    u32x2 r;
    asm volatile("ds_read_b64_tr_b16 %0, %1" : "=v"(r) : "v"(addr));
    return r;
}

__global__ __launch_bounds__(256, 6) void attn(
    const u16* __restrict__ Q,   // [B*H][N][64]
    const u16* __restrict__ Kg,
    const u16* __restrict__ Vg,
    u16* __restrict__ O)         // [B][N][H*64]
{
    // LDS bytes: K buf0 @0 (8KB), K buf1 @8192, V @16384 (8KB) = 24KB
    __shared__ u16 lds[12288];
    const int t    = threadIdx.x;
    const int wid  = t >> 6, lane = t & 63;
    const int lo   = lane & 15, hi = lane >> 4;

    const int g    = blockIdx.x;             // 0..2047
    const int slot = g >> 3;
    const int bh   = ((slot & 7) << 3) + (g & 7);   // head-batch: XCD-affine
    const int a    = slot >> 3;
    const int kq   = a >> 2, a0 = a & 3;
    const int rk   = 7 - kq;                 // reverse: longest blocks dispatch first
    const int qt   = 4 * rk + ((rk & 1) ? 3 - a0 : a0);

    const size_t base = (size_t)bh * SEQ * 64;
    const int qbase = qt * 64 + wid * 16;
    const unsigned ldsb = (unsigned)(uintptr_t)lds;

    // staging geometry (verified): pre-swizzled K source, subtiled V source
    int srcK[2], srcV[2];
    unsigned dstK[2], dstV[2];
#pragma unroll
    for (int ti = 0; ti < 2; ti++) {
        int o   = t * 8 + ti * 2048;
        int row = o >> 6;
        int colb = ((o & 63) * 2) ^ ((row & 7) << 4);
        srcK[ti] = row * 64 + (colb >> 1);
        dstK[ti] = ldsb + o * 2;              // K buf0 region
        int st = o >> 9;
        int kv = (st >> 2) * 32 + ((o >> 4) & 31);
        int d  = (st & 3) * 16 + (o & 15);
        srcV[ti] = kv * 64 + d;
        dstV[ti] = ldsb + 16384u + o * 2;     // V region (single)
    }

    // Q fragments (B-operand): lane holds Q[qbase+lo][h*32+hi*8+..] (pre-scaled)
    bf16x8 qf[2];
#pragma unroll
    for (int h = 0; h < 2; h++)
        qf[h] = *reinterpret_cast<const bf16x8*>(Q + base + (size_t)(qbase + lo) * 64 + h * 32 + hi * 8);
    asm volatile("" : "+v"(qf[0]), "+v"(qf[1]));

    // all-ones A-fragment for l-sum MFMA
    bf16x8 ones;
    {
        union { u16 uu[8]; bf16x8 v; } ov;
#pragma unroll
        for (int e = 0; e < 8; e++) ov.uu[e] = 0x3F80;   // bf16 1.0
        ones = ov.v;
    }

    float m_run = -3.0e38f;
    f32x4 acc[4], lacc = (f32x4){0.f, 0.f, 0.f, 0.f};
#pragma unroll
    for (int dt = 0; dt < 4; dt++) acc[dt] = (f32x4){0.f, 0.f, 0.f, 0.f};

    // loop-invariant tr16 base (V single buffer) -> addresses hoisted
    const unsigned vtb = ldsb + 16384u + (unsigned)((hi * 64 + lo * 4) * 2);

    // prologue: stage K(0) -> buf 0
    {
        const u16* Kt = Kg + base;
#pragma unroll
        for (int ti = 0; ti < 2; ti++) gload16(Kt + srcK[ti], dstK[ti]);
        asm volatile("s_waitcnt vmcnt(0)" ::: "memory");
    }

    for (int j = 0; j <= qt; j++) {
        const int p = j & 1;
        __builtin_amdgcn_s_barrier();        // V readers + K(j) landed (prev vmcnt(0))
        {
            const u16* Vt = Vg + base + (size_t)j * 4096;
#pragma unroll
            for (int ti = 0; ti < 2; ti++) gload16(Vt + srcV[ti], dstV[ti]);
            if (j < qt) {
                const u16* Kt = Kg + base + (size_t)(j + 1) * 4096;
                const unsigned bs = (unsigned)((p ^ 1) * 8192);
#pragma unroll
                for (int ti = 0; ti < 2; ti++) gload16(Kt + srcK[ti], dstK[ti] + bs);
            }
        }
        __builtin_amdgcn_sched_barrier(0);

        const char* Kcur = (const char*)lds + p * 8192;
        // S^T = K Q^T: lane holds S[q=qbase+lo][kv=j*64+kt*16+hi*4+r]
        f32x4 s[4];
#pragma unroll
        for (int kh = 0; kh < 2; kh++) {
            bf16x8 kfa[2][2];
#pragma unroll
            for (int k2 = 0; k2 < 2; k2++)
#pragma unroll
                for (int h = 0; h < 2; h++)
                    kfa[k2][h] = *reinterpret_cast<const bf16x8*>(
                        Kcur + ((kh * 2 + k2) * 16 + lo) * 128 + ((h * 64 + hi * 16) ^ ((lo & 7) << 4)));
            __builtin_amdgcn_s_setprio(1);
#pragma unroll
            for (int k2 = 0; k2 < 2; k2++) {
                f32x4 a2 = (f32x4){0.f, 0.f, 0.f, 0.f};
#pragma unroll
                for (int h = 0; h < 2; h++)
                    a2 = __builtin_amdgcn_mfma_f32_16x16x32_bf16(kfa[k2][h], qf[h], a2, 0, 0, 0);
                s[kh * 2 + k2] = a2;
            }
            __builtin_amdgcn_s_setprio(0);
        }
        if (j == qt) {                       // diagonal: causal mask (local indices)
            const int ql = wid * 16 + lo;
#pragma unroll
            for (int kt = 0; kt < 4; kt++)
#pragma unroll
                for (int r = 0; r < 4; r++)
                    if (kt * 16 + hi * 4 + r > ql) s[kt][r] = -1.0e30f;
        }
        // online softmax (log2 domain, Q pre-scaled), defer-max THR=8
        float vm = s[0][0];
#pragma unroll
        for (int kt = 0; kt < 4; kt++)
#pragma unroll
            for (int r = 0; r < 4; r++) vm = fmaxf(vm, s[kt][r]);
        vm = fmaxf(vm, __shfl_xor(vm, 16));
        vm = fmaxf(vm, __shfl_xor(vm, 32));
        if (!__all(vm <= m_run + 8.0f)) {
            float nm = fmaxf(m_run, vm);
            float sc = exp2f(m_run - nm);
            m_run = nm;
            lacc *= sc;                      // l rescale (lane-local, vector)
#pragma unroll
            for (int dt = 0; dt < 4; dt++)
#pragma unroll
                for (int r = 0; r < 4; r++) acc[dt][r] *= sc;   // cols=q=lo: lane-local
        }
#pragma unroll
        for (int kt = 0; kt < 4; kt++)
#pragma unroll
            for (int r = 0; r < 4; r++)
                s[kt][r] = exp2f(s[kt][r] - m_run);
        // pack P into PV B-fragments (kappa: e<4 -> kv=4hi+e; e>=4 -> 16+4hi+(e-4))
        bf16x8 pa[2];
        {
            union { u16 uu[8]; bf16x8 v; } q0, q1;
#pragma unroll
            for (int e = 0; e < 4; e++) {
                q0.uu[e]     = f2bf(s[0][e]);
                q0.uu[4 + e] = f2bf(s[1][e]);
                q1.uu[e]     = f2bf(s[2][e]);
                q1.uu[4 + e] = f2bf(s[3][e]);
            }
            pa[0] = q0.v;
            pa[1] = q1.v;
        }
        // l-sum on the MFMA pipe: every C element of column q equals sum_kv P
        lacc = __builtin_amdgcn_mfma_f32_16x16x32_bf16(ones, pa[0], lacc, 0, 0, 0);
        lacc = __builtin_amdgcn_mfma_f32_16x16x32_bf16(ones, pa[1], lacc, 0, 0, 0);

        // wait V(j) (issued this iter, hidden under QK+softmax); K(j+1) stays in flight
        if (j < qt) {
            asm volatile("s_waitcnt vmcnt(2)" ::: "memory");
        } else {
            asm volatile("s_waitcnt vmcnt(0)" ::: "memory");
        }
        __builtin_amdgcn_s_barrier();        // all waves' V(j) landed
        __builtin_amdgcn_sched_barrier(0);

        // PV swapped: acc[dt] = mfma(A=V^T frag, B=P) -> C[row=d][col=q=lo]
#pragma unroll
        for (int pr = 0; pr < 2; pr++) {
            u32x2 tv[2][2][2];
#pragma unroll
            for (int d2 = 0; d2 < 2; d2++)
#pragma unroll
                for (int h = 0; h < 2; h++)
#pragma unroll
                    for (int sel = 0; sel < 2; sel++)
                        tv[d2][h][sel] = tr16(vtb + (unsigned)(((h * 4 + pr * 2 + d2) * 512 + sel * 256) * 2));
            asm volatile("s_waitcnt lgkmcnt(0)" ::: "memory");
            __builtin_amdgcn_sched_barrier(0);
            __builtin_amdgcn_s_setprio(1);
#pragma unroll
            for (int d2 = 0; d2 < 2; d2++) {
#pragma unroll
                for (int h = 0; h < 2; h++) {
                    union { unsigned int w[4]; bf16x8 v; } bv;
                    bv.w[0] = tv[d2][h][0][0];
                    bv.w[1] = tv[d2][h][0][1];
                    bv.w[2] = tv[d2][h][1][0];
                    bv.w[3] = tv[d2][h][1][1];
                    acc[pr * 2 + d2] = __builtin_amdgcn_mfma_f32_16x16x32_bf16(bv.v, pa[h], acc[pr * 2 + d2], 0, 0, 0);
                }
            }
            __builtin_amdgcn_s_setprio(0);
        }
        // K(j+1) landed before next iteration's barrier (cross-wave guarantee)
        asm volatile("s_waitcnt vmcnt(0)" ::: "memory");
    }

    // epilogue: l is lane-local (all lacc elements equal the full column sum)
    const float inv = 1.0f / lacc[0];
    const int b = bh >> 4, hh = bh & 15;
    const size_t orow = ((size_t)(b * SEQ + qbase + lo)) * 1024 + hh * 64;
#pragma unroll
    for (int dt = 0; dt < 4; dt++) {
        union { u16 uu[4]; uint2 d2; } pk;
#pragma unroll
        for (int r = 0; r < 4; r++) pk.uu[r] = f2bf(acc[dt][r] * inv);
        *reinterpret_cast<uint2*>(O + orow + dt * 16 + hi * 4) = pk.d2;
    }
}

extern "C" void kernel_launch(void* const* d_in, const int* in_sizes, int n_in,
                              void* d_out, int out_size, void* d_ws, size_t ws_size,
                              hipStream_t stream) {
    const float* x  = (const float*)d_in[0];
    const float* Wq = (const float*)d_in[1];
    const float* Wk = (const float*)d_in[2];
    const float* Wv = (const float*)d_in[3];
    const float* Wo = (const float*)d_in[4];
    const float* bo = (const float*)d_in[5];
    float* out = (float*)d_out;

    char* ws = (char*)d_ws;
    u16* xb  = (u16*)ws;                              // 16 MiB, then weights contiguous
    u16* wqb = (u16*)(ws + 16777216);
    u16* wkb = wqb + 1048576;
    u16* wvb = wkb + 1048576;
    u16* wob = wvb + 1048576;
    u16* q   = (u16*)(ws + 16777216 + 8388608);       // [B][H][N][D] bf16
    u16* k   = q + 8388608;
    u16* v   = k + 8388608;
    u16* ao  = v + 8388608;                           // [B][N][H*64] bf16

    castk_all<<<3072, 256, 0, stream>>>(x, Wq, Wk, Wv, Wo, xb);

    gemm_pipe<0><<<dim3(ROWS / 256, 24), 512, 0, stream>>>(
        xb, wqb, wkb, wvb, q, k, v, nullptr, nullptr);

    attn<<<2048, 256, 0, stream>>>(q, k, v, ao);

    gemm_pipe<1><<<dim3(ROWS / 256, MODEL_DIM / 128), 512, 0, stream>>>(
        ao, wob, nullptr, nullptr, nullptr, nullptr, nullptr, out, bo);
}

// Round 15
// 153.064 us; speedup vs baseline: 1.9179x; 1.0741x over previous
//
#include <hip/hip_runtime.h>
#include <hip/hip_bf16.h>

typedef unsigned short u16;
typedef __attribute__((ext_vector_type(8))) __bf16 bf16x8;
typedef __attribute__((ext_vector_type(4))) float f32x4;
typedef __attribute__((ext_vector_type(2))) unsigned int u32x2;

#define MODEL_DIM 1024
#define NUM_HEADS 16
#define HEAD_DIM  64
#define BATCH     4
#define SEQ       2048
#define ROWS      (BATCH*SEQ)     // 8192

static __device__ __forceinline__ u16 f2bf(float f) {
    union { __hip_bfloat16 h; u16 u; } cv;
    cv.h = __float2bfloat16(f);
    return cv.u;
}

static __device__ __forceinline__ unsigned cvtpk(float lo, float hi) {
    unsigned d;
    asm volatile("v_cvt_pk_bf16_f32 %0, %1, %2" : "=v"(d) : "v"(lo), "v"(hi));
    return d;
}

static __device__ __forceinline__ float max3f(float a, float b, float c) {
    float d;
    asm volatile("v_max3_f32 %0, %1, %2, %3" : "=v"(d) : "v"(a), "v"(b), "v"(c));
    return d;
}

static __device__ __forceinline__ void gload16(const u16* g, unsigned lds_byte) {
    __builtin_amdgcn_global_load_lds(
        (const __attribute__((address_space(1))) unsigned int*)g,
        (__attribute__((address_space(3))) unsigned int*)(uintptr_t)lds_byte,
        16, 0, 0);
}

// ---------------- fused cast f32 -> bf16 (x + 4 weights, contiguous out) ----
__global__ void castk_all(const float* __restrict__ x,
                          const float* __restrict__ w0, const float* __restrict__ w1,
                          const float* __restrict__ w2, const float* __restrict__ w3,
                          u16* __restrict__ out) {
    const int total = ROWS * MODEL_DIM + 4 * MODEL_DIM * MODEL_DIM;  // 12.58M
    int i = (blockIdx.x * blockDim.x + threadIdx.x) * 4;
    int stride = gridDim.x * blockDim.x * 4;
    for (; i < total; i += stride) {
        const float* src;
        int off;
        if (i < ROWS * MODEL_DIM) { src = x; off = i; }
        else {
            int j = i - ROWS * MODEL_DIM;
            int w = j >> 20;
            off = j & 1048575;
            src = (w == 0) ? w0 : (w == 1) ? w1 : (w == 2) ? w2 : w3;
        }
        float4 v = *reinterpret_cast<const float4*>(src + off);
        ushort4 o;
        o.x = f2bf(v.x); o.y = f2bf(v.y); o.z = f2bf(v.z); o.w = f2bf(v.w);
        *reinterpret_cast<ushort4*>(out + i) = o;
    }
}

// ---------------- pipelined NT GEMM: 256x128 tile, dbuf + counted vmcnt ----
// R13 structure with ONE barrier per K-step (inner lockstep barriers removed;
// dbuf hazard audit: iter-k readers vs iter-k+2 writers both bounded by the
// top barrier, so per-phase barriers were redundant).

static __device__ __forceinline__ bf16x8 frag_read(const char* base, int row, int h,
                                                   int lo, int hi) {
    return *reinterpret_cast<const bf16x8*>(
        base + row * 128 + ((h * 64 + hi * 16) ^ ((lo & 7) << 4)));
}

template<int EPI>
__global__ __launch_bounds__(512, 2) void gemm_pipe(
    const u16* __restrict__ A,
    const u16* __restrict__ Wq, const u16* __restrict__ Wk, const u16* __restrict__ Wv,
    u16* __restrict__ qO, u16* __restrict__ kO, u16* __restrict__ vO,
    float* __restrict__ outF, const float* __restrict__ bias)
{
    __shared__ u16 As[2 * 16384];    // 2 x 32KB (256 rows x 64 cols)
    __shared__ u16 Bs[2 * 8192];     // 2 x 16KB (128 rows x 64 cols)
    const int t    = threadIdx.x;
    const int wid  = t >> 6;
    const int lane = t & 63;
    const int lo   = lane & 15, hi = lane >> 4;
    const int bm   = blockIdx.x * 256;
    int mat, bn;
    const u16* W;
    u16* outB = nullptr;
    float qscale = 1.0f;
    if (EPI == 0) {
        mat = blockIdx.y >> 3;
        bn  = (blockIdx.y & 7) * 128;
        W   = (mat == 0) ? Wq : (mat == 1) ? Wk : Wv;
        outB = (mat == 0) ? qO : (mat == 1) ? kO : vO;
        qscale = (mat == 0) ? 0.18033688f : 1.0f;   // 0.125*log2(e)
    } else {
        bn = blockIdx.y * 128;
        W  = Wq;                      // Wo passed in slot 0
    }
    const int wr = wid >> 1, wc = wid & 1;
    const int K = MODEL_DIM;
    const unsigned AsB = (unsigned)(uintptr_t)As;
    const unsigned BsB = (unsigned)(uintptr_t)Bs;

    const u16* aSrc[4]; unsigned aDst[4];
    const u16* bSrc[2]; unsigned bDst[2];
#pragma unroll
    for (int ti = 0; ti < 4; ti++) {
        int o = t * 8 + ti * 4096;
        int row = o >> 6;
        int colb = ((o & 63) * 2) ^ ((row & 7) << 4);
        aSrc[ti] = A + (size_t)(bm + row) * K + (colb >> 1);
        aDst[ti] = (unsigned)(o * 2);
    }
#pragma unroll
    for (int ti = 0; ti < 2; ti++) {
        int o = t * 8 + ti * 4096;
        int row = o >> 6;
        int colb = ((o & 63) * 2) ^ ((row & 7) << 4);
        bSrc[ti] = W + (size_t)(bn + row) * K + (colb >> 1);
        bDst[ti] = (unsigned)(o * 2);
    }

    f32x4 acc[4][4];
#pragma unroll
    for (int m = 0; m < 4; m++)
#pragma unroll
        for (int n = 0; n < 4; n++) acc[m][n] = (f32x4){0.f, 0.f, 0.f, 0.f};

#pragma unroll
    for (int ti = 0; ti < 4; ti++) gload16(aSrc[ti], AsB + aDst[ti]);
#pragma unroll
    for (int ti = 0; ti < 2; ti++) gload16(bSrc[ti], BsB + bDst[ti]);

    for (int kt = 0; kt < 16; kt++) {
        const int p = kt & 1;
        if (kt < 15) {
            const int ko = (kt + 1) * 64;
            const unsigned pa = (unsigned)((p ^ 1) * 32768);
            const unsigned pb = (unsigned)((p ^ 1) * 16384);
#pragma unroll
            for (int ti = 0; ti < 4; ti++) gload16(aSrc[ti] + ko, AsB + pa + aDst[ti]);
#pragma unroll
            for (int ti = 0; ti < 2; ti++) gload16(bSrc[ti] + ko, BsB + pb + bDst[ti]);
            asm volatile("s_waitcnt vmcnt(6)" ::: "memory");
        } else {
            asm volatile("s_waitcnt vmcnt(0)" ::: "memory");
        }
        __builtin_amdgcn_s_barrier();
        __builtin_amdgcn_sched_barrier(0);

        const char* Ab = (const char*)As + p * 32768;
        const char* Bb = (const char*)Bs + p * 16384;
#pragma unroll
        for (int kk = 0; kk < 2; kk++) {
            bf16x8 bfr[4];
#pragma unroll
            for (int n = 0; n < 4; n++)
                bfr[n] = frag_read(Bb, wc * 64 + n * 16 + lo, kk, lo, hi);
#pragma unroll
            for (int mh = 0; mh < 2; mh++) {
                bf16x8 af[2];
#pragma unroll
                for (int m2 = 0; m2 < 2; m2++)
                    af[m2] = frag_read(Ab, wr * 64 + (mh * 2 + m2) * 16 + lo, kk, lo, hi);
                __builtin_amdgcn_s_setprio(1);
#pragma unroll
                for (int m2 = 0; m2 < 2; m2++)
#pragma unroll
                    for (int n = 0; n < 4; n++)
                        acc[mh * 2 + m2][n] = __builtin_amdgcn_mfma_f32_16x16x32_bf16(af[m2], bfr[n], acc[mh * 2 + m2][n], 0, 0, 0);
                __builtin_amdgcn_s_setprio(0);
            }
        }
    }

#pragma unroll
    for (int m = 0; m < 4; m++)
#pragma unroll
        for (int n = 0; n < 4; n++)
#pragma unroll
            for (int r = 0; r < 4; r++) {
                int row = bm + wr * 64 + m * 16 + hi * 4 + r;
                int col = bn + wc * 64 + n * 16 + lo;
                if (EPI == 0) {
                    int b = row >> 11, np = row & 2047;
                    int hh = col >> 6, dd = col & 63;
                    outB[(((size_t)(b * NUM_HEADS + hh) * SEQ + np) << 6) + dd] = f2bf(acc[m][n][r] * qscale);
                } else {
                    outF[(size_t)row * MODEL_DIM + col] = acc[m][n][r] + bias[col];
                }
            }
}

// ---------------- flash attention v15 ------------------------------------
// R14 core (V single-buffer, counted vmcnt, l-sum MFMA, longest-first) with
// VALU trims: v_max3 tree for the max-reduce, v_cvt_pk_bf16_f32 for P-pack
// and the output pack.

static __device__ __forceinline__ u32x2 tr16(unsigned int addr) {
    u32x2 r;
    asm volatile("ds_read_b64_tr_b16 %0, %1" : "=v"(r) : "v"(addr));
    return r;
}

__global__ __launch_bounds__(256, 6) void attn(
    const u16* __restrict__ Q,   // [B*H][N][64]
    const u16* __restrict__ Kg,
    const u16* __restrict__ Vg,
    u16* __restrict__ O)         // [B][N][H*64]
{
    // LDS bytes: K buf0 @0 (8KB), K buf1 @8192, V @16384 (8KB) = 24KB
    __shared__ u16 lds[12288];
    const int t    = threadIdx.x;
    const int wid  = t >> 6, lane = t & 63;
    const int lo   = lane & 15, hi = lane >> 4;

    const int g    = blockIdx.x;             // 0..2047
    const int slot = g >> 3;
    const int bh   = ((slot & 7) << 3) + (g & 7);   // head-batch: XCD-affine
    const int a    = slot >> 3;
    const int kq   = a >> 2, a0 = a & 3;
    const int rk   = 7 - kq;                 // longest blocks dispatch first
    const int qt   = 4 * rk + ((rk & 1) ? 3 - a0 : a0);

    const size_t base = (size_t)bh * SEQ * 64;
    const int qbase = qt * 64 + wid * 16;
    const unsigned ldsb = (unsigned)(uintptr_t)lds;

    // staging geometry (verified): pre-swizzled K source, subtiled V source
    int srcK[2], srcV[2];
    unsigned dstK[2], dstV[2];
#pragma unroll
    for (int ti = 0; ti < 2; ti++) {
        int o   = t * 8 + ti * 2048;
        int row = o >> 6;
        int colb = ((o & 63) * 2) ^ ((row & 7) << 4);
        srcK[ti] = row * 64 + (colb >> 1);
        dstK[ti] = ldsb + o * 2;              // K buf0 region
        int st = o >> 9;
        int kv = (st >> 2) * 32 + ((o >> 4) & 31);
        int d  = (st & 3) * 16 + (o & 15);
        srcV[ti] = kv * 64 + d;
        dstV[ti] = ldsb + 16384u + o * 2;     // V region (single)
    }

    // Q fragments (B-operand): lane holds Q[qbase+lo][h*32+hi*8+..] (pre-scaled)
    bf16x8 qf[2];
#pragma unroll
    for (int h = 0; h < 2; h++)
        qf[h] = *reinterpret_cast<const bf16x8*>(Q + base + (size_t)(qbase + lo) * 64 + h * 32 + hi * 8);
    asm volatile("" : "+v"(qf[0]), "+v"(qf[1]));

    // all-ones A-fragment for l-sum MFMA
    bf16x8 ones;
    {
        union { u16 uu[8]; bf16x8 v; } ov;
#pragma unroll
        for (int e = 0; e < 8; e++) ov.uu[e] = 0x3F80;   // bf16 1.0
        ones = ov.v;
    }

    float m_run = -3.0e38f;
    f32x4 acc[4], lacc = (f32x4){0.f, 0.f, 0.f, 0.f};
#pragma unroll
    for (int dt = 0; dt < 4; dt++) acc[dt] = (f32x4){0.f, 0.f, 0.f, 0.f};

    // loop-invariant tr16 base (V single buffer) -> addresses hoisted
    const unsigned vtb = ldsb + 16384u + (unsigned)((hi * 64 + lo * 4) * 2);

    // prologue: stage K(0) -> buf 0
    {
        const u16* Kt = Kg + base;
#pragma unroll
        for (int ti = 0; ti < 2; ti++) gload16(Kt + srcK[ti], dstK[ti]);
        asm volatile("s_waitcnt vmcnt(0)" ::: "memory");
    }

    for (int j = 0; j <= qt; j++) {
        const int p = j & 1;
        __builtin_amdgcn_s_barrier();        // V readers + K(j) landed (prev vmcnt(0))
        {
            const u16* Vt = Vg + base + (size_t)j * 4096;
#pragma unroll
            for (int ti = 0; ti < 2; ti++) gload16(Vt + srcV[ti], dstV[ti]);
            if (j < qt) {
                const u16* Kt = Kg + base + (size_t)(j + 1) * 4096;
                const unsigned bs = (unsigned)((p ^ 1) * 8192);
#pragma unroll
                for (int ti = 0; ti < 2; ti++) gload16(Kt + srcK[ti], dstK[ti] + bs);
            }
        }
        __builtin_amdgcn_sched_barrier(0);

        const char* Kcur = (const char*)lds + p * 8192;
        // S^T = K Q^T: lane holds S[q=qbase+lo][kv=j*64+kt*16+hi*4+r]
        f32x4 s[4];
#pragma unroll
        for (int kh = 0; kh < 2; kh++) {
            bf16x8 kfa[2][2];
#pragma unroll
            for (int k2 = 0; k2 < 2; k2++)
#pragma unroll
                for (int h = 0; h < 2; h++)
                    kfa[k2][h] = *reinterpret_cast<const bf16x8*>(
                        Kcur + ((kh * 2 + k2) * 16 + lo) * 128 + ((h * 64 + hi * 16) ^ ((lo & 7) << 4)));
            __builtin_amdgcn_s_setprio(1);
#pragma unroll
            for (int k2 = 0; k2 < 2; k2++) {
                f32x4 a2 = (f32x4){0.f, 0.f, 0.f, 0.f};
#pragma unroll
                for (int h = 0; h < 2; h++)
                    a2 = __builtin_amdgcn_mfma_f32_16x16x32_bf16(kfa[k2][h], qf[h], a2, 0, 0, 0);
                s[kh * 2 + k2] = a2;
            }
            __builtin_amdgcn_s_setprio(0);
        }
        if (j == qt) {                       // diagonal: causal mask (local indices)
            const int ql = wid * 16 + lo;
#pragma unroll
            for (int kt = 0; kt < 4; kt++)
#pragma unroll
                for (int r = 0; r < 4; r++)
                    if (kt * 16 + hi * 4 + r > ql) s[kt][r] = -1.0e30f;
        }
        // online softmax (log2 domain, Q pre-scaled), defer-max THR=8
        // max over 16 values via v_max3 tree (7 max3 + 1 max, depth 3)
        float t0 = max3f(s[0][0], s[0][1], s[0][2]);
        float t1 = max3f(s[0][3], s[1][0], s[1][1]);
        float t2 = max3f(s[1][2], s[1][3], s[2][0]);
        float t3 = max3f(s[2][1], s[2][2], s[2][3]);
        float t4 = max3f(s[3][0], s[3][1], s[3][2]);
        float u0 = max3f(t0, t1, t2);
        float u1 = max3f(t3, t4, s[3][3]);
        float vm = fmaxf(u0, u1);
        vm = fmaxf(vm, __shfl_xor(vm, 16));
        vm = fmaxf(vm, __shfl_xor(vm, 32));
        if (!__all(vm <= m_run + 8.0f)) {
            float nm = fmaxf(m_run, vm);
            float sc = exp2f(m_run - nm);
            m_run = nm;
            lacc *= sc;                      // l rescale (lane-local, vector)
#pragma unroll
            for (int dt = 0; dt < 4; dt++)
#pragma unroll
                for (int r = 0; r < 4; r++) acc[dt][r] *= sc;   // cols=q=lo: lane-local
        }
#pragma unroll
        for (int kt = 0; kt < 4; kt++)
#pragma unroll
            for (int r = 0; r < 4; r++)
                s[kt][r] = exp2f(s[kt][r] - m_run);
        // pack P via v_cvt_pk_bf16_f32 (kappa order preserved: word pairs are
        // consecutive elements of each s[kt])
        bf16x8 pa[2];
        {
            union { unsigned w[4]; bf16x8 v; } q0, q1;
            q0.w[0] = cvtpk(s[0][0], s[0][1]);
            q0.w[1] = cvtpk(s[0][2], s[0][3]);
            q0.w[2] = cvtpk(s[1][0], s[1][1]);
            q0.w[3] = cvtpk(s[1][2], s[1][3]);
            q1.w[0] = cvtpk(s[2][0], s[2][1]);
            q1.w[1] = cvtpk(s[2][2], s[2][3]);
            q1.w[2] = cvtpk(s[3][0], s[3][1]);
            q1.w[3] = cvtpk(s[3][2], s[3][3]);
            pa[0] = q0.v;
            pa[1] = q1.v;
        }
        // l-sum on the MFMA pipe: every C element of column q equals sum_kv P
        lacc = __builtin_amdgcn_mfma_f32_16x16x32_bf16(ones, pa[0], lacc, 0, 0, 0);
        lacc = __builtin_amdgcn_mfma_f32_16x16x32_bf16(ones, pa[1], lacc, 0, 0, 0);

        // wait V(j) (issued this iter, hidden under QK+softmax); K(j+1) in flight
        if (j < qt) {
            asm volatile("s_waitcnt vmcnt(2)" ::: "memory");
        } else {
            asm volatile("s_waitcnt vmcnt(0)" ::: "memory");
        }
        __builtin_amdgcn_s_barrier();        // all waves' V(j) landed
        __builtin_amdgcn_sched_barrier(0);

        // PV swapped: acc[dt] = mfma(A=V^T frag, B=P) -> C[row=d][col=q=lo]
#pragma unroll
        for (int pr = 0; pr < 2; pr++) {
            u32x2 tv[2][2][2];
#pragma unroll
            for (int d2 = 0; d2 < 2; d2++)
#pragma unroll
                for (int h = 0; h < 2; h++)
#pragma unroll
                    for (int sel = 0; sel < 2; sel++)
                        tv[d2][h][sel] = tr16(vtb + (unsigned)(((h * 4 + pr * 2 + d2) * 512 + sel * 256) * 2));
            asm volatile("s_waitcnt lgkmcnt(0)" ::: "memory");
            __builtin_amdgcn_sched_barrier(0);
            __builtin_amdgcn_s_setprio(1);
#pragma unroll
            for (int d2 = 0; d2 < 2; d2++) {
#pragma unroll
                for (int h = 0; h < 2; h++) {
                    union { unsigned int w[4]; bf16x8 v; } bv;
                    bv.w[0] = tv[d2][h][0][0];
                    bv.w[1] = tv[d2][h][0][1];
                    bv.w[2] = tv[d2][h][1][0];
                    bv.w[3] = tv[d2][h][1][1];
                    acc[pr * 2 + d2] = __builtin_amdgcn_mfma_f32_16x16x32_bf16(bv.v, pa[h], acc[pr * 2 + d2], 0, 0, 0);
                }
            }
            __builtin_amdgcn_s_setprio(0);
        }
        // K(j+1) landed before next iteration's barrier (cross-wave guarantee)
        asm volatile("s_waitcnt vmcnt(0)" ::: "memory");
    }

    // epilogue: l is lane-local (all lacc elements equal the full column sum)
    const float inv = 1.0f / lacc[0];
    const int b = bh >> 4, hh = bh & 15;
    const size_t orow = ((size_t)(b * SEQ + qbase + lo)) * 1024 + hh * 64;
#pragma unroll
    for (int dt = 0; dt < 4; dt++) {
        union { unsigned w[2]; uint2 d2; } pk;
        pk.w[0] = cvtpk(acc[dt][0] * inv, acc[dt][1] * inv);
        pk.w[1] = cvtpk(acc[dt][2] * inv, acc[dt][3] * inv);
        *reinterpret_cast<uint2*>(O + orow + dt * 16 + hi * 4) = pk.d2;
    }
}

extern "C" void kernel_launch(void* const* d_in, const int* in_sizes, int n_in,
                              void* d_out, int out_size, void* d_ws, size_t ws_size,
                              hipStream_t stream) {
    const float* x  = (const float*)d_in[0];
    const float* Wq = (const float*)d_in[1];
    const float* Wk = (const float*)d_in[2];
    const float* Wv = (const float*)d_in[3];
    const float* Wo = (const float*)d_in[4];
    const float* bo = (const float*)d_in[5];
    float* out = (float*)d_out;

    char* ws = (char*)d_ws;
    u16* xb  = (u16*)ws;                              // 16 MiB, then weights contiguous
    u16* wqb = (u16*)(ws + 16777216);
    u16* wkb = wqb + 1048576;
    u16* wvb = wkb + 1048576;
    u16* wob = wvb + 1048576;
    u16* q   = (u16*)(ws + 16777216 + 8388608);       // [B][H][N][D] bf16
    u16* k   = q + 8388608;
    u16* v   = k + 8388608;
    u16* ao  = v + 8388608;                           // [B][N][H*64] bf16

    castk_all<<<3072, 256, 0, stream>>>(x, Wq, Wk, Wv, Wo, xb);

    gemm_pipe<0><<<dim3(ROWS / 256, 24), 512, 0, stream>>>(
        xb, wqb, wkb, wvb, q, k, v, nullptr, nullptr);

    attn<<<2048, 256, 0, stream>>>(q, k, v, ao);

    gemm_pipe<1><<<dim3(ROWS / 256, MODEL_DIM / 128), 512, 0, stream>>>(
        ao, wob, nullptr, nullptr, nullptr, nullptr, nullptr, out, bo);
}